// Round 8
// baseline (713.366 us; speedup 1.0000x reference)
//
#include <hip/hip_runtime.h>
#include <math.h>

// FNO3D: B=8, C=3, H=W=64, T=32, WIDTH=32, modes 8x8x8 (4 corners), 4 layers.
// Round 16 (on R7 base):
//  - T5 stored packed u32 (packhl per component) by k_invy; fuse's invx_reg
//    uses unpack8 instead of split8 -- BIT-IDENTICAL (consumer only uses the
//    hi/lo pair, which packhl stores exactly). -96 VALU/thread in fuse.
//  - k_mix2 split 4-way over batches (1024 blocks, 2 bb each): was 1
//    block/CU / 4 waves -- occupancy-starved. Weight re-reads stay L3-hot.
//  - float4 staging loads in k_xdft / k_ydft.
// All changes bit-identical: absmax must stay exactly 1.525879e-05.
//
// ws floats: X 33,554,432 | T1 16,777,216 | T2 4,194,304 | T3 1,048,576 | T4 1,048,576

#define TWO_PI 6.2831853071795864769f

typedef short bf16x8 __attribute__((ext_vector_type(8)));
typedef float f32x4 __attribute__((ext_vector_type(4)));
typedef float v2f __attribute__((ext_vector_type(2)));

__device__ __forceinline__ f32x4 mfma16(bf16x8 a, bf16x8 b, f32x4 c) {
    return __builtin_amdgcn_mfma_f32_16x16x32_bf16(a, b, c, 0, 0, 0);
}

__device__ __forceinline__ void split8(float4 a, float4 b, bf16x8& h, bf16x8& l) {
    float f[8] = {a.x, a.y, a.z, a.w, b.x, b.y, b.z, b.w};
    #pragma unroll
    for (int i = 0; i < 8; ++i) {
        unsigned u = __float_as_uint(f[i]);
        h[i] = (short)(u >> 16);
        float hf = __uint_as_float(u & 0xFFFF0000u);
        float lf = f[i] - hf;
        l[i] = (short)(__float_as_uint(lf) >> 16);
    }
}

// pack f32 -> u32 (bf16hi<<16 | bf16lo); both truncated like split8
__device__ __forceinline__ unsigned packhl(float f) {
    unsigned u = __float_as_uint(f);
    unsigned hi = u & 0xFFFF0000u;
    float lf = f - __uint_as_float(hi);
    return hi | (__float_as_uint(lf) >> 16);
}

__device__ __forceinline__ void unpack8(uint4 a, uint4 b, bf16x8& h, bf16x8& l) {
    unsigned u[8] = {a.x, a.y, a.z, a.w, b.x, b.y, b.z, b.w};
    #pragma unroll
    for (int i = 0; i < 8; ++i) {
        h[i] = (short)(u[i] >> 16);
        l[i] = (short)(u[i] & 0xFFFFu);
    }
}

__device__ __forceinline__ v2f make2(float x) { v2f r; r.x = x; r.y = x; return r; }
__device__ __forceinline__ v2f fma2(v2f a, v2f b, v2f c) { return __builtin_elementwise_fma(a, b, c); }

// packed gelu via A&S 7.1.26 erf (|err|<=1.5e-7)
__device__ __forceinline__ v2f gelu2(v2f v) {
    v2f u = v * 0.70710678118654752f;
    v2f a = __builtin_elementwise_abs(u);
    v2f den = fma2(a, make2(0.3275911f), make2(1.0f));
    v2f t; t.x = __builtin_amdgcn_rcpf(den.x); t.y = __builtin_amdgcn_rcpf(den.y);
    v2f p = t * (0.254829592f + t * (-0.284496736f + t * (1.421413741f +
            t * (-1.453152027f + t * 1.061405429f))));
    v2f e; e.x = __expf(-u.x * u.x); e.y = __expf(-u.y * u.y);
    v2f m = fma2(-p, e, make2(1.0f));
    v2f erfu = __builtin_elementwise_copysign(m, u);
    return 0.5f * v * (1.0f + erfu);
}

__device__ __forceinline__ void gelu4(f32x4& q) {
    v2f p0; p0.x = q[0]; p0.y = q[1];
    v2f p1; p1.x = q[2]; p1.y = q[3];
    p0 = gelu2(p0); p1 = gelu2(p1);
    q[0] = p0.x; q[1] = p0.y; q[2] = p1.x; q[3] = p1.y;
}

// ---- forward t-DFT matrix A-frag: G[kr][t], kr=l15, t=quad*8+j (K=32 full)
// G[2k][t] = cos(2pi k t/32), G[2k+1][t] = -sin(2pi k t/32)
__device__ __forceinline__ void make_fwd_A(int l15, int quad, bf16x8& Gh, bf16x8& Gl) {
    int k = l15 >> 1;
    float s0, c0, ds, dc;
    __sincosf((float)(k * quad * 8) * (TWO_PI / 32.0f), &s0, &c0);
    __sincosf((float)k * (TWO_PI / 32.0f), &ds, &dc);
    float m[8];
    float cc = c0, ss = s0;
    #pragma unroll
    for (int j = 0; j < 8; ++j) {
        m[j] = (l15 & 1) ? -ss : cc;
        float nc = cc * dc - ss * ds;
        float ns = ss * dc + cc * ds;
        cc = nc; ss = ns;
    }
    split8(make_float4(m[0], m[1], m[2], m[3]),
           make_float4(m[4], m[5], m[6], m[7]), Gh, Gl);
}

// forward t-DFT via MFMA from packed-u32 rows [(spl*32+c)][36] -> T1
__device__ __forceinline__ void fwd_tdft(const unsigned* up, int b, int sp0,
                                         float2* __restrict__ T1,
                                         int wb, int l15, int quad,
                                         bf16x8 Gh, bf16x8 Gl) {
    #pragma unroll
    for (int nt = 0; nt < 4; ++nt) {
        int r = wb + nt * 16 + l15;                 // row = spl*32 + c (wave-local)
        const uint4* p = (const uint4*)(up + r * 36 + quad * 8);
        bf16x8 bh, bl; unpack8(p[0], p[1], bh, bl);
        f32x4 d = {0.f, 0.f, 0.f, 0.f};
        d = mfma16(Gh, bh, d);
        d = mfma16(Gl, bh, d);
        d = mfma16(Gh, bl, d);
        int c = r & 31, spl = r >> 5;
        float4* ob = (float4*)(T1 + ((long)(b * 32 + c) * 4096 + sp0 + spl) * 8 + quad * 2);
        *ob = make_float4(d[0], d[1], d[2], d[3]);
    }
}

// ---- inverse-x DFT matrix A-frag: A[m=(spl,ri_out)][k=(kxi,ri_in)], S folded.
__device__ __forceinline__ void make_invx_A(int x0, int l15, int quad, bf16x8& Ah, bf16x8& Al) {
    int spl = l15 >> 1, ro = l15 & 1;
    float xx = (float)(x0 + spl);
    const float S = 1.0f / 131072.0f;
    float f[8];
    #pragma unroll
    for (int m = 0; m < 4; ++m) {
        int kxi = quad * 4 + m;
        float kx = (float)(kxi < 8 ? kxi : kxi - 16);
        float sn, cs;
        __sincosf(kx * xx * (TWO_PI / 64.0f), &sn, &cs);
        f[2 * m]     = ro ? S * sn : S * cs;
        f[2 * m + 1] = ro ? S * cs : -S * sn;
    }
    split8(make_float4(f[0], f[1], f[2], f[3]),
           make_float4(f[4], f[5], f[6], f[7]), Ah, Al);
}

// inverse-x MFMA from per-thread registers (packed T5 loads): -> ts (f32)
// bit-identical to the old split8 path: packhl stored exactly (hi,lo).
__device__ __forceinline__ void invx_reg(float* smem, const uint2 v[4], int half, int wave,
                                         int nt2, int l15, int quad, bf16x8 xAh, bf16x8 xAl) {
    uint4 a = make_uint4(v[0].x, v[0].y, v[1].x, v[1].y);
    uint4 b = make_uint4(v[2].x, v[2].y, v[3].x, v[3].y);
    bf16x8 bh, bl; unpack8(a, b, bh, bl);
    f32x4 d = {0.f, 0.f, 0.f, 0.f};
    d = mfma16(xAh, bh, d);
    d = mfma16(xAl, bh, d);
    d = mfma16(xAh, bl, d);
    int ol = (wave * 2 + nt2) * 2 + (l15 >> 3), kt = l15 & 7;
    int o = half * 16 + ol;
    #pragma unroll
    for (int reg = 0; reg < 4; ++reg) {
        int m_ = quad * 4 + reg, spl = m_ >> 1, ri = m_ & 1;
        smem[o * 132 + spl * 16 + kt * 2 + ri] = d[reg];
    }
}

// ---- lift: x_t + grid -> p conv -> X(packed) [b][sp][t][c]; fused MFMA t-DFT -> T1 ----
__global__ __launch_bounds__(256) void k_lift(const float* __restrict__ xt,
                                              const float* __restrict__ pw,
                                              const float* __restrict__ pb,
                                              unsigned* __restrict__ X,
                                              float2* __restrict__ T1) {
    __shared__ unsigned xs[9216];       // [(spl*32+c)][36] packed hi|lo
    int gg = blockIdx.x;                // XCD swizzle: batch b = gg&7 stays on one XCD
    int g = ((gg & 7) << 9) | (gg >> 3);
    int spt = g & 511, b = g >> 9;
    int sp0 = spt * 8;
    int y = sp0 >> 6, x0 = sp0 & 63;
    int tid = threadIdx.x;
    int t = tid & 31, spl = tid >> 5;
    int sp = sp0 + spl;
    float a0 = xt[(b * 3 + 0) * 4096 + sp];
    float a1 = xt[(b * 3 + 1) * 4096 + sp];
    float a2 = xt[(b * 3 + 2) * 4096 + sp];
    float gy = y * (1.0f / 63.0f), gx = (x0 + spl) * (1.0f / 63.0f), gt = t * (1.0f / 31.0f);
    float v[32];
    #pragma unroll
    for (int c = 0; c < 32; ++c) {
        const float* w = pw + c * 6;
        v[c] = pb[c] + w[0] * a0 + w[1] * a1 + w[2] * a2
             + w[3] * gy + w[4] * gx + w[5] * gt;
    }
    unsigned pk[32];
    #pragma unroll
    for (int c = 0; c < 32; ++c) pk[c] = packhl(v[c]);
    unsigned* xg2 = X + (((long)(b * 4096 + sp)) * 32 + t) * 32;
    #pragma unroll
    for (int j = 0; j < 8; ++j)
        ((uint4*)xg2)[j] = make_uint4(pk[4*j], pk[4*j+1], pk[4*j+2], pk[4*j+3]);
    #pragma unroll
    for (int c = 0; c < 32; ++c)
        xs[(spl * 32 + c) * 36 + t] = pk[c];          // 2-way bank alias: free
    int wave = tid >> 6, lane = tid & 63, l15 = lane & 15, quad = lane >> 4;
    bf16x8 Gh, Gl; make_fwd_A(l15, quad, Gh, Gl);
    __syncthreads();
    fwd_tdft(xs, b, sp0, T1, wave * 64, l15, quad, Gh, Gl);
}

// ------- forward x-DFT (E/O split): T1 -> T2 (16 modes) -------
__global__ __launch_bounds__(256) void k_xdft(const float2* __restrict__ T1, float2* __restrict__ T2) {
    __shared__ float2 s[1024];
    __shared__ float2 tw[64];
    int g = blockIdx.x;              // bc*32 + ypair ; 8192 blocks
    int ypair = g & 31; int bc = g >> 5;
    long base = ((long)bc * 64 + ypair * 2) * 512;
    int tid = threadIdx.x;
    {   // float4 staging (1024 float2 = 512 float4)
        float4* s4 = (float4*)s;
        const float4* src4 = (const float4*)(T1 + base);
        #pragma unroll
        for (int r = 0; r < 2; ++r) s4[tid + r * 256] = src4[tid + r * 256];
    }
    if (tid < 64) { float sn, cs; __sincosf(tid * (TWO_PI / 64.0f), &sn, &cs); tw[tid] = make_float2(cs, sn); }
    __syncthreads();
    // in-place butterfly: x<32 -> E at x, O at x+32 (per half-row)
    #pragma unroll
    for (int r = 0; r < 2; ++r) {
        int j = tid + r * 256;       // 512 pairs: (half, x<32, kt)
        int half = j >> 8, rem = j & 255;
        int idx = half * 512 + rem;
        float2 a = s[idx], b2 = s[idx + 256];
        s[idx] = make_float2(a.x + b2.x, a.y + b2.y);
        s[idx + 256] = make_float2(a.x - b2.x, a.y - b2.y);
    }
    __syncthreads();
    int half = tid >> 7, jj = tid & 127;
    int kxi = jj >> 3, kt = jj & 7;
    int kx = kxi < 8 ? kxi : kxi + 48;
    const float2* row = s + half * 512 + (kx & 1) * 256;
    float sr = 0.f, si = 0.f;
    for (int x = 0; x < 32; ++x) {
        float2 w = tw[(kx * x) & 63];
        float2 a = row[x * 8 + kt];
        sr += a.x * w.x + a.y * w.y;
        si += a.y * w.x - a.x * w.y;
    }
    T2[((long)bc * 64 + ypair * 2 + half) * 128 + jj] = make_float2(sr, si);
}

// ------- forward y-DFT (E/O split): T2 -> T3 (16 modes) -------
__global__ __launch_bounds__(128) void k_ydft(const float2* __restrict__ T2, float2* __restrict__ T3) {
    __shared__ float2 s[512];
    __shared__ float2 tw[64];
    int g = blockIdx.x;              // bc*16 + kx ; 4096 blocks
    int kx = g & 15; int bc = g >> 4;
    int tid = threadIdx.x;
    {   // float4 staging: per y, 8 float2 = 4 float4
        float4* s4 = (float4*)s;
        #pragma unroll
        for (int r = 0; r < 2; ++r) {
            int k = tid + r * 128;   // 256 float4
            int y = k >> 2, j = k & 3;
            s4[k] = ((const float4*)(T2 + ((long)bc * 64 + y) * 128 + kx * 8))[j];
        }
    }
    if (tid < 64) { float sn, cs; __sincosf(tid * (TWO_PI / 64.0f), &sn, &cs); tw[tid] = make_float2(cs, sn); }
    __syncthreads();
    #pragma unroll
    for (int r = 0; r < 2; ++r) {
        int j = tid + r * 128;       // 256 pairs: y<32 x kt
        float2 a = s[j], b2 = s[j + 256];
        s[j] = make_float2(a.x + b2.x, a.y + b2.y);
        s[j + 256] = make_float2(a.x - b2.x, a.y - b2.y);
    }
    __syncthreads();
    int kyi = tid >> 3, kt = tid & 7;
    int ky = kyi < 8 ? kyi : kyi + 48;
    const float2* row = s + (ky & 1) * 256;
    float sr = 0.f, si = 0.f;
    for (int y = 0; y < 32; ++y) {
        float2 w = tw[(ky * y) & 63];
        float2 a = row[y * 8 + kt];
        sr += a.x * w.x + a.y * w.y;
        si += a.y * w.x - a.x * w.y;
    }
    T3[((long)bc * 256 + kyi * 16 + kx) * 8 + kt] = make_float2(sr, si);
}

// -------- mode mix, 4-way batch-split (1024 blocks, 2 bb each) --------
__global__ __launch_bounds__(256) void k_mix2(const float2* __restrict__ T3,
                                              const float* __restrict__ wr,
                                              const float* __restrict__ wi,
                                              float2* __restrict__ T4, int layer) {
    __shared__ float2 s[576];        // (i*2+bbl)*9 + kt
    int g = blockIdx.x;              // mode*4 + bbh ; 1024 blocks
    int bbh = g & 3, mode = g >> 2;
    int kyi = mode >> 4, kxi = mode & 15;
    int tid = threadIdx.x;
    #pragma unroll
    for (int r = 0; r < 2; ++r) {
        int k = tid + r * 256;       // 512 elems: i(32) x bbl(2) x kt(8)
        int i = k >> 4, bbl = (k >> 3) & 1, kt = k & 7;
        s[(i * 2 + bbl) * 9 + kt] =
            T3[((long)((bbh * 2 + bbl) * 32 + i) * 256 + mode) * 8 + kt];
    }
    __syncthreads();
    int corner = (kyi >= 8 ? 1 : 0) + (kxi >= 8 ? 2 : 0);
    long wbase = (long)(layer * 4 + corner) * 524288 + (long)(kyi & 7) * 64 + (long)(kxi & 7) * 8;
    int o = tid >> 3, kt = tid & 7;
    long wb = wbase + (long)o * 512 + kt;
    float2 acc[2];
    acc[0] = make_float2(0.f, 0.f); acc[1] = make_float2(0.f, 0.f);
    for (int i = 0; i < 32; ++i) {
        float r = wr[wb + (long)i * 16384], im = wi[wb + (long)i * 16384];
        #pragma unroll
        for (int bbl = 0; bbl < 2; ++bbl) {
            float2 a = s[(i * 2 + bbl) * 9 + kt];
            acc[bbl].x += a.x * r - a.y * im;
            acc[bbl].y += a.x * im + a.y * r;
        }
    }
    #pragma unroll
    for (int bbl = 0; bbl < 2; ++bbl)
        T4[((long)((bbh * 2 + bbl) * 32 + o) * 256 + mode) * 8 + kt] = acc[bbl];
}

// ------- inverse y (P/M pairing): T4 -> T5 (packed u32, T2 space) -------
__global__ __launch_bounds__(256) void k_invy(const float2* __restrict__ T4, uint2* __restrict__ T5) {
    __shared__ float2 s[128];
    __shared__ float2 tw[64];
    __shared__ float2 pmP[56], pmM[56];   // j=1..7 x kt
    int g = blockIdx.x;              // bc*16 + kx ; 4096 blocks
    int kx = g & 15; int bc = g >> 4;
    int tid = threadIdx.x;
    if (tid < 128) {
        int kyi = tid >> 3, kt = tid & 7;
        s[tid] = T4[((long)bc * 256 + kyi * 16 + kx) * 8 + kt];
    } else if (tid < 192) {
        int m = tid - 128; float sn, cs; __sincosf(m * (TWO_PI / 64.0f), &sn, &cs); tw[m] = make_float2(cs, sn);
    }
    __syncthreads();
    if (tid < 56) {
        int j = (tid >> 3) + 1, kt = tid & 7;
        float2 a = s[j * 8 + kt], b2 = s[(16 - j) * 8 + kt];
        pmP[tid] = make_float2(a.x + b2.x, a.y + b2.y);
        pmM[tid] = make_float2(a.x - b2.x, a.y - b2.y);
    }
    __syncthreads();
    #pragma unroll
    for (int r = 0; r < 2; ++r) {
        int j = tid + r * 256;
        int y = j >> 3, kt = j & 7;
        float2 A0 = s[kt], A8 = s[64 + kt];
        float2 w8 = tw[(8 * y) & 63];
        float sr = A0.x + A8.x * w8.x + A8.y * w8.y;
        float si = A0.y + A8.y * w8.x - A8.x * w8.y;
        #pragma unroll
        for (int jj = 1; jj < 8; ++jj) {
            float2 w = tw[(jj * y) & 63];
            float2 P = pmP[(jj - 1) * 8 + kt], M = pmM[(jj - 1) * 8 + kt];
            sr += P.x * w.x - M.y * w.y;
            si += P.y * w.x + M.x * w.y;
        }
        T5[((long)bc * 64 + y) * 128 + kx * 8 + kt] = make_uint2(packhl(sr), packhl(si));
    }
}

// ---- inverse-t DFT matrix frags (used as MFMA **B** operand, values = M[t][kr]):
// lane n=t (=l15, t-half th), k-slot kr = quad*8+j; quads 2,3 zero (K pad 16->32).
__device__ __forceinline__ void make_invt_A(int l15, int quad, bf16x8 Ah[2], bf16x8 Al[2]) {
    #pragma unroll
    for (int th = 0; th < 2; ++th) {
        float m[8];
        if (quad < 2) {
            int tt = th * 16 + l15;
            #pragma unroll
            for (int kk = 0; kk < 4; ++kk) {
                int k = quad * 4 + kk;
                float sn, cs;
                __sincosf((float)(k * tt) * (TWO_PI / 32.0f), &sn, &cs);
                float w = k ? 2.0f : 1.0f;
                m[2 * kk] = w * cs;
                m[2 * kk + 1] = -w * sn;
            }
        } else {
            #pragma unroll
            for (int j = 0; j < 8; ++j) m[j] = 0.f;
        }
        split8(make_float4(m[0], m[1], m[2], m[3]),
               make_float4(m[4], m[5], m[6], m[7]), Ah[th], Al[th]);
    }
}

// ---- fuse3: MFMA pointwise + MFMA inverse-x (reg-direct packed T5) + transposed
//      MFMA inverse-t (direct accumulate) + gelu2; X update; MFMA fwd t-DFT ----
__global__ __launch_bounds__(256) void k_fuse3(unsigned* __restrict__ X, const uint2* __restrict__ T5,
                                               const float* __restrict__ pww,
                                               const float* __restrict__ pwb,
                                               float2* __restrict__ T1, int layer) {
    __shared__ float smem[9216];     // ts [0..4223] | packed acts/D 256x36 u32 (union)
    int gg = blockIdx.x;             // XCD swizzle: batch b = gg&7 stays on one XCD
    int g = ((gg & 7) << 9) | (gg >> 3);
    int spt = g & 511, b = g >> 9;
    int sp0 = spt * 8;
    int y = sp0 >> 6, x0 = sp0 & 63;
    int tid = threadIdx.x;
    int wave = tid >> 6, lane = tid & 63, l15 = lane & 15, quad = lane >> 4;
    int wb = wave * 64;
    // direct packed-T5 loads (each cell consumed by exactly this thread)
    uint2 t5v[2][2][4];
    #pragma unroll
    for (int half = 0; half < 2; ++half)
        #pragma unroll
        for (int nt2 = 0; nt2 < 2; ++nt2) {
            int ol = (wave * 2 + nt2) * 2 + (l15 >> 3);
            const uint2* rp = T5 + ((long)((b * 32 + half * 16 + ol) * 64 + y)) * 128 + (l15 & 7);
            #pragma unroll
            for (int m = 0; m < 4; ++m)
                t5v[half][nt2][m] = rp[(quad * 4 + m) * 8];
        }
    const float* wl = pww + layer * 1024;
    const float* bl = pwb + layer * 32;
    bf16x8 wah[2], wal[2];
    f32x4 acc[2][4];
    #pragma unroll
    for (int mt = 0; mt < 2; ++mt) {
        const float4* p = (const float4*)(wl + (mt * 16 + l15) * 32 + quad * 8);
        split8(p[0], p[1], wah[mt], wal[mt]);
        float4 bv = *(const float4*)(bl + mt * 16 + quad * 4);
        f32x4 bi; bi[0] = bv.x; bi[1] = bv.y; bi[2] = bv.z; bi[3] = bv.w;
        #pragma unroll
        for (int nt = 0; nt < 4; ++nt) acc[mt][nt] = bi;
    }
    #pragma unroll
    for (int nt = 0; nt < 4; ++nt) {
        int pt = wb + nt * 16 + l15;
        int spl = pt >> 5, t = pt & 31;
        const uint4* xp = (const uint4*)(X + (((long)(b * 4096 + sp0 + spl)) * 32 + t) * 32 + quad * 8);
        bf16x8 bh, blo; unpack8(xp[0], xp[1], bh, blo);
        #pragma unroll
        for (int mt = 0; mt < 2; ++mt) {
            acc[mt][nt] = mfma16(wah[mt], bh, acc[mt][nt]);
            acc[mt][nt] = mfma16(wal[mt], bh, acc[mt][nt]);
            acc[mt][nt] = mfma16(wah[mt], blo, acc[mt][nt]);
        }
    }
    bf16x8 Ah[2], Al[2];
    make_invt_A(l15, quad, Ah, Al);
    bf16x8 xAh, xAl;
    make_invx_A(x0, l15, quad, xAh, xAl);
    // inverse-x from registers -> ts (no staging barriers)
    #pragma unroll
    for (int half = 0; half < 2; ++half)
        #pragma unroll
        for (int nt2 = 0; nt2 < 2; ++nt2)
            invx_reg(smem, t5v[half][nt2], half, wave, nt2, l15, quad, xAh, xAl);
    __syncthreads();                 // ts complete
    // spectrum frags (A operand of the transposed inverse-t)
    bf16x8 Bh[2][2], Bl[2][2];
    #pragma unroll
    for (int sph = 0; sph < 2; ++sph) {
        int spl = 2 * wave + sph;
        #pragma unroll
        for (int ch = 0; ch < 2; ++ch) {
            float4 q0 = make_float4(0.f, 0.f, 0.f, 0.f), q1 = q0;
            if (quad < 2) {
                const float4* p = (const float4*)((float2*)smem + (ch * 16 + l15) * 66 + spl * 8 + quad * 4);
                q0 = p[0]; q1 = p[1];
            }
            split8(q0, q1, Bh[sph][ch], Bl[sph][ch]);
        }
    }
    __syncthreads();                 // ts reads done; smem free -> packed acts
    // transposed inverse-t: acc[ch][sph*2+th] += S^T x M^T  (register-direct)
    #pragma unroll
    for (int sph = 0; sph < 2; ++sph)
        #pragma unroll
        for (int ch = 0; ch < 2; ++ch)
            #pragma unroll
            for (int th = 0; th < 2; ++th) {
                int nt = sph * 2 + th;
                acc[ch][nt] = mfma16(Bh[sph][ch], Ah[th], acc[ch][nt]);
                acc[ch][nt] = mfma16(Bl[sph][ch], Ah[th], acc[ch][nt]);
                acc[ch][nt] = mfma16(Bh[sph][ch], Al[th], acc[ch][nt]);
            }
    bf16x8 Gh, Gl; make_fwd_A(l15, quad, Gh, Gl);
    #pragma unroll
    for (int mt = 0; mt < 2; ++mt)
        #pragma unroll
        for (int nt = 0; nt < 4; ++nt) gelu4(acc[mt][nt]);
    unsigned* up = (unsigned*)smem;
    #pragma unroll
    for (int mt = 0; mt < 2; ++mt)
        #pragma unroll
        for (int nt = 0; nt < 4; ++nt) {
            int pt = wb + nt * 16 + l15;
            int spl = pt >> 5, t = pt & 31;
            int o0 = mt * 16 + quad * 4;
            unsigned pk0 = packhl(acc[mt][nt][0]), pk1 = packhl(acc[mt][nt][1]);
            unsigned pk2 = packhl(acc[mt][nt][2]), pk3 = packhl(acc[mt][nt][3]);
            *(uint4*)(X + (((long)(b * 4096 + sp0 + spl)) * 32 + t) * 32 + o0) =
                make_uint4(pk0, pk1, pk2, pk3);
            // transposed packed store (2-way bank alias: free)
            up[(spl * 32 + o0 + 0) * 36 + t] = pk0;
            up[(spl * 32 + o0 + 1) * 36 + t] = pk1;
            up[(spl * 32 + o0 + 2) * 36 + t] = pk2;
            up[(spl * 32 + o0 + 3) * 36 + t] = pk3;
        }
    __syncthreads();
    // MFMA forward t-DFT for next layer
    fwd_tdft(up, b, sp0, T1, wb, l15, quad, Gh, Gl);
}

// ---- fuse3_last: MFMA layer-3 pointwise + inverse-x (reg-direct) + transposed
//      inverse-t + q1 head (packed acts) + q2 -> out ----
__global__ __launch_bounds__(256) void k_fuse3_last(const unsigned* __restrict__ X, const uint2* __restrict__ T5,
                                                    const float* __restrict__ pww, const float* __restrict__ pwb,
                                                    const float* __restrict__ q1w, const float* __restrict__ q1b,
                                                    const float* __restrict__ q2w, const float* __restrict__ q2b,
                                                    float* __restrict__ out) {
    __shared__ float smem[9408];     // ts | packed acts 256x36 (union); q2w at 9216
    int gg = blockIdx.x;             // XCD swizzle
    int g = ((gg & 7) << 9) | (gg >> 3);
    int spt = g & 511, b = g >> 9;
    int sp0 = spt * 8;
    int y = sp0 >> 6, x0 = sp0 & 63;
    int tid = threadIdx.x;
    int wave = tid >> 6, lane = tid & 63, l15 = lane & 15, quad = lane >> 4;
    int wb = wave * 64;
    uint2 t5v[2][2][4];
    #pragma unroll
    for (int half = 0; half < 2; ++half)
        #pragma unroll
        for (int nt2 = 0; nt2 < 2; ++nt2) {
            int ol = (wave * 2 + nt2) * 2 + (l15 >> 3);
            const uint2* rp = T5 + ((long)((b * 32 + half * 16 + ol) * 64 + y)) * 128 + (l15 & 7);
            #pragma unroll
            for (int m = 0; m < 4; ++m)
                t5v[half][nt2][m] = rp[(quad * 4 + m) * 8];
        }
    if (tid < 192) smem[9216 + tid] = q2w[tid];
    const float* wl = pww + 3 * 1024;
    const float* bl = pwb + 3 * 32;
    bf16x8 wah[2], wal[2];
    f32x4 acc[2][4];
    #pragma unroll
    for (int mt = 0; mt < 2; ++mt) {
        const float4* p = (const float4*)(wl + (mt * 16 + l15) * 32 + quad * 8);
        split8(p[0], p[1], wah[mt], wal[mt]);
        float4 bv = *(const float4*)(bl + mt * 16 + quad * 4);
        f32x4 bi; bi[0] = bv.x; bi[1] = bv.y; bi[2] = bv.z; bi[3] = bv.w;
        #pragma unroll
        for (int nt = 0; nt < 4; ++nt) acc[mt][nt] = bi;
    }
    #pragma unroll
    for (int nt = 0; nt < 4; ++nt) {
        int pt = wb + nt * 16 + l15;
        int spl = pt >> 5, t = pt & 31;
        const uint4* xp = (const uint4*)(X + (((long)(b * 4096 + sp0 + spl)) * 32 + t) * 32 + quad * 8);
        bf16x8 bh, blo; unpack8(xp[0], xp[1], bh, blo);
        #pragma unroll
        for (int mt = 0; mt < 2; ++mt) {
            acc[mt][nt] = mfma16(wah[mt], bh, acc[mt][nt]);
            acc[mt][nt] = mfma16(wal[mt], bh, acc[mt][nt]);
            acc[mt][nt] = mfma16(wah[mt], blo, acc[mt][nt]);
        }
    }
    bf16x8 Ah[2], Al[2];
    make_invt_A(l15, quad, Ah, Al);
    bf16x8 xAh, xAl;
    make_invx_A(x0, l15, quad, xAh, xAl);
    #pragma unroll
    for (int half = 0; half < 2; ++half)
        #pragma unroll
        for (int nt2 = 0; nt2 < 2; ++nt2)
            invx_reg(smem, t5v[half][nt2], half, wave, nt2, l15, quad, xAh, xAl);
    __syncthreads();                 // ts complete
    bf16x8 Bh[2][2], Bl[2][2];
    #pragma unroll
    for (int sph = 0; sph < 2; ++sph) {
        int spl = 2 * wave + sph;
        #pragma unroll
        for (int ch = 0; ch < 2; ++ch) {
            float4 q0 = make_float4(0.f, 0.f, 0.f, 0.f), q1 = q0;
            if (quad < 2) {
                const float4* p = (const float4*)((float2*)smem + (ch * 16 + l15) * 66 + spl * 8 + quad * 4);
                q0 = p[0]; q1 = p[1];
            }
            split8(q0, q1, Bh[sph][ch], Bl[sph][ch]);
        }
    }
    __syncthreads();                 // ts reads done; smem free -> packed acts
    #pragma unroll
    for (int sph = 0; sph < 2; ++sph)
        #pragma unroll
        for (int ch = 0; ch < 2; ++ch)
            #pragma unroll
            for (int th = 0; th < 2; ++th) {
                int nt = sph * 2 + th;
                acc[ch][nt] = mfma16(Bh[sph][ch], Ah[th], acc[ch][nt]);
                acc[ch][nt] = mfma16(Bl[sph][ch], Ah[th], acc[ch][nt]);
                acc[ch][nt] = mfma16(Bh[sph][ch], Al[th], acc[ch][nt]);
            }
    #pragma unroll
    for (int mt = 0; mt < 2; ++mt)
        #pragma unroll
        for (int nt = 0; nt < 4; ++nt) gelu4(acc[mt][nt]);
    unsigned* up = (unsigned*)smem;
    #pragma unroll
    for (int mt = 0; mt < 2; ++mt)
        #pragma unroll
        for (int nt = 0; nt < 4; ++nt) {
            int pt = wb + nt * 16 + l15;
            int o0 = mt * 16 + quad * 4;
            *(uint4*)(up + pt * 36 + o0) =
                make_uint4(packhl(acc[mt][nt][0]), packhl(acc[mt][nt][1]),
                           packhl(acc[mt][nt][2]), packhl(acc[mt][nt][3]));
        }
    __syncthreads();
    // head: q1 (MFMA, packed-acts B) + gelu2 + q2 (lane-local + shfl reduce)
    bf16x8 qah[4], qal[4];
    f32x4 qbv[4];
    #pragma unroll
    for (int mt = 0; mt < 4; ++mt) {
        const float4* p = (const float4*)(q1w + (mt * 16 + l15) * 32 + quad * 8);
        split8(p[0], p[1], qah[mt], qal[mt]);
        float4 bv = *(const float4*)(q1b + mt * 16 + quad * 4);
        qbv[mt][0] = bv.x; qbv[mt][1] = bv.y; qbv[mt][2] = bv.z; qbv[mt][3] = bv.w;
    }
    const float* q2l = smem + 9216;
    float q2b0 = q2b[0], q2b1 = q2b[1], q2b2 = q2b[2];
    float oc0[4], oc1[4], oc2[4];
    #pragma unroll
    for (int nt = 0; nt < 4; ++nt) {
        int pt = wb + nt * 16 + l15;
        const uint4* bp = (const uint4*)(up + pt * 36 + quad * 8);
        bf16x8 bh, blo; unpack8(bp[0], bp[1], bh, blo);
        float p0 = 0.f, p1 = 0.f, p2 = 0.f;
        #pragma unroll
        for (int mt = 0; mt < 4; ++mt) {
            f32x4 h = qbv[mt];
            h = mfma16(qah[mt], bh, h);
            h = mfma16(qal[mt], bh, h);
            h = mfma16(qah[mt], blo, h);
            gelu4(h);
            #pragma unroll
            for (int reg = 0; reg < 4; ++reg) {
                int hh = mt * 16 + quad * 4 + reg;
                p0 += q2l[hh] * h[reg];
                p1 += q2l[64 + hh] * h[reg];
                p2 += q2l[128 + hh] * h[reg];
            }
        }
        p0 += __shfl_xor(p0, 16); p0 += __shfl_xor(p0, 32);
        p1 += __shfl_xor(p1, 16); p1 += __shfl_xor(p1, 32);
        p2 += __shfl_xor(p2, 16); p2 += __shfl_xor(p2, 32);
        oc0[nt] = p0 + q2b0; oc1[nt] = p1 + q2b1; oc2[nt] = p2 + q2b2;
    }
    __syncthreads();                 // act reads done; smem[0..863] becomes out-stage
    if (quad == 0) {
        #pragma unroll
        for (int nt = 0; nt < 4; ++nt) {
            int pt = wb + nt * 16 + l15;
            int spl = pt >> 5, t = pt & 31;
            smem[(t * 3 + 0) * 9 + spl] = oc0[nt];
            smem[(t * 3 + 1) * 9 + spl] = oc1[nt];
            smem[(t * 3 + 2) * 9 + spl] = oc2[nt];
        }
    }
    __syncthreads();
    for (int m = tid; m < 768; m += 256) {
        int u = m >> 3, spl = m & 7;
        out[((long)(b * 96 + u)) * 4096 + sp0 + spl] = smem[u * 9 + spl];
    }
}

extern "C" void kernel_launch(void* const* d_in, const int* in_sizes, int n_in,
                              void* d_out, int out_size, void* d_ws, size_t ws_size,
                              hipStream_t stream) {
    const float* xt  = (const float*)d_in[0];
    const float* pw  = (const float*)d_in[1];
    const float* pb  = (const float*)d_in[2];
    const float* swr = (const float*)d_in[3];
    const float* swi = (const float*)d_in[4];
    const float* pww = (const float*)d_in[5];
    const float* pwb = (const float*)d_in[6];
    const float* q1w = (const float*)d_in[7];
    const float* q1b = (const float*)d_in[8];
    const float* q2w = (const float*)d_in[9];
    const float* q2b = (const float*)d_in[10];
    float* out = (float*)d_out;

    unsigned* X  = (unsigned*)d_ws;
    float2* T1 = (float2*)((float*)d_ws + 33554432);
    float2* T2 = (float2*)((float*)T1 + 16777216);
    float2* T3 = (float2*)((float*)T2 + 4194304);
    float2* T4 = (float2*)((float*)T3 + 1048576);

    k_lift<<<4096, 256, 0, stream>>>(xt, pw, pb, X, T1);
    for (int l = 0; l < 4; ++l) {
        k_xdft<<<8192, 256, 0, stream>>>(T1, T2);
        k_ydft<<<4096, 128, 0, stream>>>(T2, T3);
        k_mix2<<<1024, 256, 0, stream>>>(T3, swr, swi, T4, l);
        k_invy<<<4096, 256, 0, stream>>>(T4, (uint2*)T2);
        if (l < 3)
            k_fuse3<<<4096, 256, 0, stream>>>(X, (const uint2*)T2, pww, pwb, T1, l);
        else
            k_fuse3_last<<<4096, 256, 0, stream>>>(X, (const uint2*)T2, pww, pwb, q1w, q1b, q2w, q2b, out);
    }
}

// Round 9
// 707.467 us; speedup vs baseline: 1.0083x; 1.0083x over previous
//
#include <hip/hip_runtime.h>
#include <math.h>

// FNO3D: B=8, C=3, H=W=64, T=32, WIDTH=32, modes 8x8x8 (4 corners), 4 layers.
// Round 17: surgical revert of R16's T5-packing (third confirmation that the
// fuse family is latency-bound: split8's float ops between T5 loads and MFMA
// are load-latency insurance -- removing them exposed the stall, +25us).
// T5 is float2 again; fuse path byte-identical to R15/R7. KEPT from R16:
// mix2 4-way batch-split (1024 blocks) and float4 staging in xdft/ydft.
//
// ws floats: X 33,554,432 | T1 16,777,216 | T2 4,194,304 | T3 1,048,576 | T4 1,048,576

#define TWO_PI 6.2831853071795864769f

typedef short bf16x8 __attribute__((ext_vector_type(8)));
typedef float f32x4 __attribute__((ext_vector_type(4)));
typedef float v2f __attribute__((ext_vector_type(2)));

__device__ __forceinline__ f32x4 mfma16(bf16x8 a, bf16x8 b, f32x4 c) {
    return __builtin_amdgcn_mfma_f32_16x16x32_bf16(a, b, c, 0, 0, 0);
}

__device__ __forceinline__ void split8(float4 a, float4 b, bf16x8& h, bf16x8& l) {
    float f[8] = {a.x, a.y, a.z, a.w, b.x, b.y, b.z, b.w};
    #pragma unroll
    for (int i = 0; i < 8; ++i) {
        unsigned u = __float_as_uint(f[i]);
        h[i] = (short)(u >> 16);
        float hf = __uint_as_float(u & 0xFFFF0000u);
        float lf = f[i] - hf;
        l[i] = (short)(__float_as_uint(lf) >> 16);
    }
}

// pack f32 -> u32 (bf16hi<<16 | bf16lo); both truncated like split8
__device__ __forceinline__ unsigned packhl(float f) {
    unsigned u = __float_as_uint(f);
    unsigned hi = u & 0xFFFF0000u;
    float lf = f - __uint_as_float(hi);
    return hi | (__float_as_uint(lf) >> 16);
}

__device__ __forceinline__ void unpack8(uint4 a, uint4 b, bf16x8& h, bf16x8& l) {
    unsigned u[8] = {a.x, a.y, a.z, a.w, b.x, b.y, b.z, b.w};
    #pragma unroll
    for (int i = 0; i < 8; ++i) {
        h[i] = (short)(u[i] >> 16);
        l[i] = (short)(u[i] & 0xFFFFu);
    }
}

__device__ __forceinline__ v2f make2(float x) { v2f r; r.x = x; r.y = x; return r; }
__device__ __forceinline__ v2f fma2(v2f a, v2f b, v2f c) { return __builtin_elementwise_fma(a, b, c); }

// packed gelu via A&S 7.1.26 erf (|err|<=1.5e-7)
__device__ __forceinline__ v2f gelu2(v2f v) {
    v2f u = v * 0.70710678118654752f;
    v2f a = __builtin_elementwise_abs(u);
    v2f den = fma2(a, make2(0.3275911f), make2(1.0f));
    v2f t; t.x = __builtin_amdgcn_rcpf(den.x); t.y = __builtin_amdgcn_rcpf(den.y);
    v2f p = t * (0.254829592f + t * (-0.284496736f + t * (1.421413741f +
            t * (-1.453152027f + t * 1.061405429f))));
    v2f e; e.x = __expf(-u.x * u.x); e.y = __expf(-u.y * u.y);
    v2f m = fma2(-p, e, make2(1.0f));
    v2f erfu = __builtin_elementwise_copysign(m, u);
    return 0.5f * v * (1.0f + erfu);
}

__device__ __forceinline__ void gelu4(f32x4& q) {
    v2f p0; p0.x = q[0]; p0.y = q[1];
    v2f p1; p1.x = q[2]; p1.y = q[3];
    p0 = gelu2(p0); p1 = gelu2(p1);
    q[0] = p0.x; q[1] = p0.y; q[2] = p1.x; q[3] = p1.y;
}

// ---- forward t-DFT matrix A-frag: G[kr][t], kr=l15, t=quad*8+j (K=32 full)
// G[2k][t] = cos(2pi k t/32), G[2k+1][t] = -sin(2pi k t/32)
__device__ __forceinline__ void make_fwd_A(int l15, int quad, bf16x8& Gh, bf16x8& Gl) {
    int k = l15 >> 1;
    float s0, c0, ds, dc;
    __sincosf((float)(k * quad * 8) * (TWO_PI / 32.0f), &s0, &c0);
    __sincosf((float)k * (TWO_PI / 32.0f), &ds, &dc);
    float m[8];
    float cc = c0, ss = s0;
    #pragma unroll
    for (int j = 0; j < 8; ++j) {
        m[j] = (l15 & 1) ? -ss : cc;
        float nc = cc * dc - ss * ds;
        float ns = ss * dc + cc * ds;
        cc = nc; ss = ns;
    }
    split8(make_float4(m[0], m[1], m[2], m[3]),
           make_float4(m[4], m[5], m[6], m[7]), Gh, Gl);
}

// forward t-DFT via MFMA from packed-u32 rows [(spl*32+c)][36] -> T1
__device__ __forceinline__ void fwd_tdft(const unsigned* up, int b, int sp0,
                                         float2* __restrict__ T1,
                                         int wb, int l15, int quad,
                                         bf16x8 Gh, bf16x8 Gl) {
    #pragma unroll
    for (int nt = 0; nt < 4; ++nt) {
        int r = wb + nt * 16 + l15;                 // row = spl*32 + c (wave-local)
        const uint4* p = (const uint4*)(up + r * 36 + quad * 8);
        bf16x8 bh, bl; unpack8(p[0], p[1], bh, bl);
        f32x4 d = {0.f, 0.f, 0.f, 0.f};
        d = mfma16(Gh, bh, d);
        d = mfma16(Gl, bh, d);
        d = mfma16(Gh, bl, d);
        int c = r & 31, spl = r >> 5;
        float4* ob = (float4*)(T1 + ((long)(b * 32 + c) * 4096 + sp0 + spl) * 8 + quad * 2);
        *ob = make_float4(d[0], d[1], d[2], d[3]);
    }
}

// ---- inverse-x DFT matrix A-frag: A[m=(spl,ri_out)][k=(kxi,ri_in)], S folded.
__device__ __forceinline__ void make_invx_A(int x0, int l15, int quad, bf16x8& Ah, bf16x8& Al) {
    int spl = l15 >> 1, ro = l15 & 1;
    float xx = (float)(x0 + spl);
    const float S = 1.0f / 131072.0f;
    float f[8];
    #pragma unroll
    for (int m = 0; m < 4; ++m) {
        int kxi = quad * 4 + m;
        float kx = (float)(kxi < 8 ? kxi : kxi - 16);
        float sn, cs;
        __sincosf(kx * xx * (TWO_PI / 64.0f), &sn, &cs);
        f[2 * m]     = ro ? S * sn : S * cs;
        f[2 * m + 1] = ro ? S * cs : -S * sn;
    }
    split8(make_float4(f[0], f[1], f[2], f[3]),
           make_float4(f[4], f[5], f[6], f[7]), Ah, Al);
}

// inverse-x MFMA from per-thread registers (direct T5 loads): -> ts (f32)
__device__ __forceinline__ void invx_reg(float* smem, const float2 v[4], int half, int wave,
                                         int nt2, int l15, int quad, bf16x8 xAh, bf16x8 xAl) {
    float f[8];
    #pragma unroll
    for (int m = 0; m < 4; ++m) { f[2 * m] = v[m].x; f[2 * m + 1] = v[m].y; }
    bf16x8 bh, bl;
    split8(make_float4(f[0], f[1], f[2], f[3]),
           make_float4(f[4], f[5], f[6], f[7]), bh, bl);
    f32x4 d = {0.f, 0.f, 0.f, 0.f};
    d = mfma16(xAh, bh, d);
    d = mfma16(xAl, bh, d);
    d = mfma16(xAh, bl, d);
    int ol = (wave * 2 + nt2) * 2 + (l15 >> 3), kt = l15 & 7;
    int o = half * 16 + ol;
    #pragma unroll
    for (int reg = 0; reg < 4; ++reg) {
        int m_ = quad * 4 + reg, spl = m_ >> 1, ri = m_ & 1;
        smem[o * 132 + spl * 16 + kt * 2 + ri] = d[reg];
    }
}

// ---- lift: x_t + grid -> p conv -> X(packed) [b][sp][t][c]; fused MFMA t-DFT -> T1 ----
__global__ __launch_bounds__(256) void k_lift(const float* __restrict__ xt,
                                              const float* __restrict__ pw,
                                              const float* __restrict__ pb,
                                              unsigned* __restrict__ X,
                                              float2* __restrict__ T1) {
    __shared__ unsigned xs[9216];       // [(spl*32+c)][36] packed hi|lo
    int gg = blockIdx.x;                // XCD swizzle: batch b = gg&7 stays on one XCD
    int g = ((gg & 7) << 9) | (gg >> 3);
    int spt = g & 511, b = g >> 9;
    int sp0 = spt * 8;
    int y = sp0 >> 6, x0 = sp0 & 63;
    int tid = threadIdx.x;
    int t = tid & 31, spl = tid >> 5;
    int sp = sp0 + spl;
    float a0 = xt[(b * 3 + 0) * 4096 + sp];
    float a1 = xt[(b * 3 + 1) * 4096 + sp];
    float a2 = xt[(b * 3 + 2) * 4096 + sp];
    float gy = y * (1.0f / 63.0f), gx = (x0 + spl) * (1.0f / 63.0f), gt = t * (1.0f / 31.0f);
    float v[32];
    #pragma unroll
    for (int c = 0; c < 32; ++c) {
        const float* w = pw + c * 6;
        v[c] = pb[c] + w[0] * a0 + w[1] * a1 + w[2] * a2
             + w[3] * gy + w[4] * gx + w[5] * gt;
    }
    unsigned pk[32];
    #pragma unroll
    for (int c = 0; c < 32; ++c) pk[c] = packhl(v[c]);
    unsigned* xg2 = X + (((long)(b * 4096 + sp)) * 32 + t) * 32;
    #pragma unroll
    for (int j = 0; j < 8; ++j)
        ((uint4*)xg2)[j] = make_uint4(pk[4*j], pk[4*j+1], pk[4*j+2], pk[4*j+3]);
    #pragma unroll
    for (int c = 0; c < 32; ++c)
        xs[(spl * 32 + c) * 36 + t] = pk[c];          // 2-way bank alias: free
    int wave = tid >> 6, lane = tid & 63, l15 = lane & 15, quad = lane >> 4;
    bf16x8 Gh, Gl; make_fwd_A(l15, quad, Gh, Gl);
    __syncthreads();
    fwd_tdft(xs, b, sp0, T1, wave * 64, l15, quad, Gh, Gl);
}

// ------- forward x-DFT (E/O split): T1 -> T2 (16 modes) -------
__global__ __launch_bounds__(256) void k_xdft(const float2* __restrict__ T1, float2* __restrict__ T2) {
    __shared__ float2 s[1024];
    __shared__ float2 tw[64];
    int g = blockIdx.x;              // bc*32 + ypair ; 8192 blocks
    int ypair = g & 31; int bc = g >> 5;
    long base = ((long)bc * 64 + ypair * 2) * 512;
    int tid = threadIdx.x;
    {   // float4 staging (1024 float2 = 512 float4)
        float4* s4 = (float4*)s;
        const float4* src4 = (const float4*)(T1 + base);
        #pragma unroll
        for (int r = 0; r < 2; ++r) s4[tid + r * 256] = src4[tid + r * 256];
    }
    if (tid < 64) { float sn, cs; __sincosf(tid * (TWO_PI / 64.0f), &sn, &cs); tw[tid] = make_float2(cs, sn); }
    __syncthreads();
    // in-place butterfly: x<32 -> E at x, O at x+32 (per half-row)
    #pragma unroll
    for (int r = 0; r < 2; ++r) {
        int j = tid + r * 256;       // 512 pairs: (half, x<32, kt)
        int half = j >> 8, rem = j & 255;
        int idx = half * 512 + rem;
        float2 a = s[idx], b2 = s[idx + 256];
        s[idx] = make_float2(a.x + b2.x, a.y + b2.y);
        s[idx + 256] = make_float2(a.x - b2.x, a.y - b2.y);
    }
    __syncthreads();
    int half = tid >> 7, jj = tid & 127;
    int kxi = jj >> 3, kt = jj & 7;
    int kx = kxi < 8 ? kxi : kxi + 48;
    const float2* row = s + half * 512 + (kx & 1) * 256;
    float sr = 0.f, si = 0.f;
    for (int x = 0; x < 32; ++x) {
        float2 w = tw[(kx * x) & 63];
        float2 a = row[x * 8 + kt];
        sr += a.x * w.x + a.y * w.y;
        si += a.y * w.x - a.x * w.y;
    }
    T2[((long)bc * 64 + ypair * 2 + half) * 128 + jj] = make_float2(sr, si);
}

// ------- forward y-DFT (E/O split): T2 -> T3 (16 modes) -------
__global__ __launch_bounds__(128) void k_ydft(const float2* __restrict__ T2, float2* __restrict__ T3) {
    __shared__ float2 s[512];
    __shared__ float2 tw[64];
    int g = blockIdx.x;              // bc*16 + kx ; 4096 blocks
    int kx = g & 15; int bc = g >> 4;
    int tid = threadIdx.x;
    {   // float4 staging: per y, 8 float2 = 4 float4
        float4* s4 = (float4*)s;
        #pragma unroll
        for (int r = 0; r < 2; ++r) {
            int k = tid + r * 128;   // 256 float4
            int y = k >> 2, j = k & 3;
            s4[k] = ((const float4*)(T2 + ((long)bc * 64 + y) * 128 + kx * 8))[j];
        }
    }
    if (tid < 64) { float sn, cs; __sincosf(tid * (TWO_PI / 64.0f), &sn, &cs); tw[tid] = make_float2(cs, sn); }
    __syncthreads();
    #pragma unroll
    for (int r = 0; r < 2; ++r) {
        int j = tid + r * 128;       // 256 pairs: y<32 x kt
        float2 a = s[j], b2 = s[j + 256];
        s[j] = make_float2(a.x + b2.x, a.y + b2.y);
        s[j + 256] = make_float2(a.x - b2.x, a.y - b2.y);
    }
    __syncthreads();
    int kyi = tid >> 3, kt = tid & 7;
    int ky = kyi < 8 ? kyi : kyi + 48;
    const float2* row = s + (ky & 1) * 256;
    float sr = 0.f, si = 0.f;
    for (int y = 0; y < 32; ++y) {
        float2 w = tw[(ky * y) & 63];
        float2 a = row[y * 8 + kt];
        sr += a.x * w.x + a.y * w.y;
        si += a.y * w.x - a.x * w.y;
    }
    T3[((long)bc * 256 + kyi * 16 + kx) * 8 + kt] = make_float2(sr, si);
}

// -------- mode mix, 4-way batch-split (1024 blocks, 2 bb each) --------
__global__ __launch_bounds__(256) void k_mix2(const float2* __restrict__ T3,
                                              const float* __restrict__ wr,
                                              const float* __restrict__ wi,
                                              float2* __restrict__ T4, int layer) {
    __shared__ float2 s[576];        // (i*2+bbl)*9 + kt
    int g = blockIdx.x;              // mode*4 + bbh ; 1024 blocks
    int bbh = g & 3, mode = g >> 2;
    int kyi = mode >> 4, kxi = mode & 15;
    int tid = threadIdx.x;
    #pragma unroll
    for (int r = 0; r < 2; ++r) {
        int k = tid + r * 256;       // 512 elems: i(32) x bbl(2) x kt(8)
        int i = k >> 4, bbl = (k >> 3) & 1, kt = k & 7;
        s[(i * 2 + bbl) * 9 + kt] =
            T3[((long)((bbh * 2 + bbl) * 32 + i) * 256 + mode) * 8 + kt];
    }
    __syncthreads();
    int corner = (kyi >= 8 ? 1 : 0) + (kxi >= 8 ? 2 : 0);
    long wbase = (long)(layer * 4 + corner) * 524288 + (long)(kyi & 7) * 64 + (long)(kxi & 7) * 8;
    int o = tid >> 3, kt = tid & 7;
    long wb = wbase + (long)o * 512 + kt;
    float2 acc[2];
    acc[0] = make_float2(0.f, 0.f); acc[1] = make_float2(0.f, 0.f);
    for (int i = 0; i < 32; ++i) {
        float r = wr[wb + (long)i * 16384], im = wi[wb + (long)i * 16384];
        #pragma unroll
        for (int bbl = 0; bbl < 2; ++bbl) {
            float2 a = s[(i * 2 + bbl) * 9 + kt];
            acc[bbl].x += a.x * r - a.y * im;
            acc[bbl].y += a.x * im + a.y * r;
        }
    }
    #pragma unroll
    for (int bbl = 0; bbl < 2; ++bbl)
        T4[((long)((bbh * 2 + bbl) * 32 + o) * 256 + mode) * 8 + kt] = acc[bbl];
}

// ------- inverse y (P/M pairing): T4 -> T5 (T2 space) -------
__global__ __launch_bounds__(256) void k_invy(const float2* __restrict__ T4, float2* __restrict__ T5) {
    __shared__ float2 s[128];
    __shared__ float2 tw[64];
    __shared__ float2 pmP[56], pmM[56];   // j=1..7 x kt
    int g = blockIdx.x;              // bc*16 + kx ; 4096 blocks
    int kx = g & 15; int bc = g >> 4;
    int tid = threadIdx.x;
    if (tid < 128) {
        int kyi = tid >> 3, kt = tid & 7;
        s[tid] = T4[((long)bc * 256 + kyi * 16 + kx) * 8 + kt];
    } else if (tid < 192) {
        int m = tid - 128; float sn, cs; __sincosf(m * (TWO_PI / 64.0f), &sn, &cs); tw[m] = make_float2(cs, sn);
    }
    __syncthreads();
    if (tid < 56) {
        int j = (tid >> 3) + 1, kt = tid & 7;
        float2 a = s[j * 8 + kt], b2 = s[(16 - j) * 8 + kt];
        pmP[tid] = make_float2(a.x + b2.x, a.y + b2.y);
        pmM[tid] = make_float2(a.x - b2.x, a.y - b2.y);
    }
    __syncthreads();
    #pragma unroll
    for (int r = 0; r < 2; ++r) {
        int j = tid + r * 256;
        int y = j >> 3, kt = j & 7;
        float2 A0 = s[kt], A8 = s[64 + kt];
        float2 w8 = tw[(8 * y) & 63];
        float sr = A0.x + A8.x * w8.x + A8.y * w8.y;
        float si = A0.y + A8.y * w8.x - A8.x * w8.y;
        #pragma unroll
        for (int jj = 1; jj < 8; ++jj) {
            float2 w = tw[(jj * y) & 63];
            float2 P = pmP[(jj - 1) * 8 + kt], M = pmM[(jj - 1) * 8 + kt];
            sr += P.x * w.x - M.y * w.y;
            si += P.y * w.x + M.x * w.y;
        }
        T5[((long)bc * 64 + y) * 128 + kx * 8 + kt] = make_float2(sr, si);
    }
}

// ---- inverse-t DFT matrix frags (used as MFMA **B** operand, values = M[t][kr]):
// lane n=t (=l15, t-half th), k-slot kr = quad*8+j; quads 2,3 zero (K pad 16->32).
__device__ __forceinline__ void make_invt_A(int l15, int quad, bf16x8 Ah[2], bf16x8 Al[2]) {
    #pragma unroll
    for (int th = 0; th < 2; ++th) {
        float m[8];
        if (quad < 2) {
            int tt = th * 16 + l15;
            #pragma unroll
            for (int kk = 0; kk < 4; ++kk) {
                int k = quad * 4 + kk;
                float sn, cs;
                __sincosf((float)(k * tt) * (TWO_PI / 32.0f), &sn, &cs);
                float w = k ? 2.0f : 1.0f;
                m[2 * kk] = w * cs;
                m[2 * kk + 1] = -w * sn;
            }
        } else {
            #pragma unroll
            for (int j = 0; j < 8; ++j) m[j] = 0.f;
        }
        split8(make_float4(m[0], m[1], m[2], m[3]),
               make_float4(m[4], m[5], m[6], m[7]), Ah[th], Al[th]);
    }
}

// ---- fuse3: MFMA pointwise + MFMA inverse-x (reg-direct T5) + transposed
//      MFMA inverse-t (direct accumulate) + gelu2; X update; MFMA fwd t-DFT ----
__global__ __launch_bounds__(256) void k_fuse3(unsigned* __restrict__ X, const float2* __restrict__ T5,
                                               const float* __restrict__ pww,
                                               const float* __restrict__ pwb,
                                               float2* __restrict__ T1, int layer) {
    __shared__ float smem[9216];     // ts [0..4223] | packed acts/D 256x36 u32 (union)
    int gg = blockIdx.x;             // XCD swizzle: batch b = gg&7 stays on one XCD
    int g = ((gg & 7) << 9) | (gg >> 3);
    int spt = g & 511, b = g >> 9;
    int sp0 = spt * 8;
    int y = sp0 >> 6, x0 = sp0 & 63;
    int tid = threadIdx.x;
    int wave = tid >> 6, lane = tid & 63, l15 = lane & 15, quad = lane >> 4;
    int wb = wave * 64;
    // direct T5 loads (each cell consumed by exactly this thread); issued
    // at entry so HBM/L2 latency hides under the pointwise MFMA section
    float2 t5v[2][2][4];
    #pragma unroll
    for (int half = 0; half < 2; ++half)
        #pragma unroll
        for (int nt2 = 0; nt2 < 2; ++nt2) {
            int ol = (wave * 2 + nt2) * 2 + (l15 >> 3);
            const float2* rp = T5 + ((long)((b * 32 + half * 16 + ol) * 64 + y)) * 128 + (l15 & 7);
            #pragma unroll
            for (int m = 0; m < 4; ++m)
                t5v[half][nt2][m] = rp[(quad * 4 + m) * 8];
        }
    const float* wl = pww + layer * 1024;
    const float* bl = pwb + layer * 32;
    bf16x8 wah[2], wal[2];
    f32x4 acc[2][4];
    #pragma unroll
    for (int mt = 0; mt < 2; ++mt) {
        const float4* p = (const float4*)(wl + (mt * 16 + l15) * 32 + quad * 8);
        split8(p[0], p[1], wah[mt], wal[mt]);
        float4 bv = *(const float4*)(bl + mt * 16 + quad * 4);
        f32x4 bi; bi[0] = bv.x; bi[1] = bv.y; bi[2] = bv.z; bi[3] = bv.w;
        #pragma unroll
        for (int nt = 0; nt < 4; ++nt) acc[mt][nt] = bi;
    }
    #pragma unroll
    for (int nt = 0; nt < 4; ++nt) {
        int pt = wb + nt * 16 + l15;
        int spl = pt >> 5, t = pt & 31;
        const uint4* xp = (const uint4*)(X + (((long)(b * 4096 + sp0 + spl)) * 32 + t) * 32 + quad * 8);
        bf16x8 bh, blo; unpack8(xp[0], xp[1], bh, blo);
        #pragma unroll
        for (int mt = 0; mt < 2; ++mt) {
            acc[mt][nt] = mfma16(wah[mt], bh, acc[mt][nt]);
            acc[mt][nt] = mfma16(wal[mt], bh, acc[mt][nt]);
            acc[mt][nt] = mfma16(wah[mt], blo, acc[mt][nt]);
        }
    }
    bf16x8 Ah[2], Al[2];
    make_invt_A(l15, quad, Ah, Al);
    bf16x8 xAh, xAl;
    make_invx_A(x0, l15, quad, xAh, xAl);
    // inverse-x from registers -> ts (no staging barriers)
    #pragma unroll
    for (int half = 0; half < 2; ++half)
        #pragma unroll
        for (int nt2 = 0; nt2 < 2; ++nt2)
            invx_reg(smem, t5v[half][nt2], half, wave, nt2, l15, quad, xAh, xAl);
    __syncthreads();                 // ts complete
    // spectrum frags (A operand of the transposed inverse-t)
    bf16x8 Bh[2][2], Bl[2][2];
    #pragma unroll
    for (int sph = 0; sph < 2; ++sph) {
        int spl = 2 * wave + sph;
        #pragma unroll
        for (int ch = 0; ch < 2; ++ch) {
            float4 q0 = make_float4(0.f, 0.f, 0.f, 0.f), q1 = q0;
            if (quad < 2) {
                const float4* p = (const float4*)((float2*)smem + (ch * 16 + l15) * 66 + spl * 8 + quad * 4);
                q0 = p[0]; q1 = p[1];
            }
            split8(q0, q1, Bh[sph][ch], Bl[sph][ch]);
        }
    }
    __syncthreads();                 // ts reads done; smem free -> packed acts
    // transposed inverse-t: acc[ch][sph*2+th] += S^T x M^T  (register-direct)
    #pragma unroll
    for (int sph = 0; sph < 2; ++sph)
        #pragma unroll
        for (int ch = 0; ch < 2; ++ch)
            #pragma unroll
            for (int th = 0; th < 2; ++th) {
                int nt = sph * 2 + th;
                acc[ch][nt] = mfma16(Bh[sph][ch], Ah[th], acc[ch][nt]);
                acc[ch][nt] = mfma16(Bl[sph][ch], Ah[th], acc[ch][nt]);
                acc[ch][nt] = mfma16(Bh[sph][ch], Al[th], acc[ch][nt]);
            }
    bf16x8 Gh, Gl; make_fwd_A(l15, quad, Gh, Gl);
    #pragma unroll
    for (int mt = 0; mt < 2; ++mt)
        #pragma unroll
        for (int nt = 0; nt < 4; ++nt) gelu4(acc[mt][nt]);
    unsigned* up = (unsigned*)smem;
    #pragma unroll
    for (int mt = 0; mt < 2; ++mt)
        #pragma unroll
        for (int nt = 0; nt < 4; ++nt) {
            int pt = wb + nt * 16 + l15;
            int spl = pt >> 5, t = pt & 31;
            int o0 = mt * 16 + quad * 4;
            unsigned pk0 = packhl(acc[mt][nt][0]), pk1 = packhl(acc[mt][nt][1]);
            unsigned pk2 = packhl(acc[mt][nt][2]), pk3 = packhl(acc[mt][nt][3]);
            *(uint4*)(X + (((long)(b * 4096 + sp0 + spl)) * 32 + t) * 32 + o0) =
                make_uint4(pk0, pk1, pk2, pk3);
            // transposed packed store (2-way bank alias: free)
            up[(spl * 32 + o0 + 0) * 36 + t] = pk0;
            up[(spl * 32 + o0 + 1) * 36 + t] = pk1;
            up[(spl * 32 + o0 + 2) * 36 + t] = pk2;
            up[(spl * 32 + o0 + 3) * 36 + t] = pk3;
        }
    __syncthreads();
    // MFMA forward t-DFT for next layer
    fwd_tdft(up, b, sp0, T1, wb, l15, quad, Gh, Gl);
}

// ---- fuse3_last: MFMA layer-3 pointwise + inverse-x (reg-direct) + transposed
//      inverse-t + q1 head (packed acts) + q2 -> out ----
__global__ __launch_bounds__(256) void k_fuse3_last(const unsigned* __restrict__ X, const float2* __restrict__ T5,
                                                    const float* __restrict__ pww, const float* __restrict__ pwb,
                                                    const float* __restrict__ q1w, const float* __restrict__ q1b,
                                                    const float* __restrict__ q2w, const float* __restrict__ q2b,
                                                    float* __restrict__ out) {
    __shared__ float smem[9408];     // ts | packed acts 256x36 (union); q2w at 9216
    int gg = blockIdx.x;             // XCD swizzle
    int g = ((gg & 7) << 9) | (gg >> 3);
    int spt = g & 511, b = g >> 9;
    int sp0 = spt * 8;
    int y = sp0 >> 6, x0 = sp0 & 63;
    int tid = threadIdx.x;
    int wave = tid >> 6, lane = tid & 63, l15 = lane & 15, quad = lane >> 4;
    int wb = wave * 64;
    float2 t5v[2][2][4];
    #pragma unroll
    for (int half = 0; half < 2; ++half)
        #pragma unroll
        for (int nt2 = 0; nt2 < 2; ++nt2) {
            int ol = (wave * 2 + nt2) * 2 + (l15 >> 3);
            const float2* rp = T5 + ((long)((b * 32 + half * 16 + ol) * 64 + y)) * 128 + (l15 & 7);
            #pragma unroll
            for (int m = 0; m < 4; ++m)
                t5v[half][nt2][m] = rp[(quad * 4 + m) * 8];
        }
    if (tid < 192) smem[9216 + tid] = q2w[tid];
    const float* wl = pww + 3 * 1024;
    const float* bl = pwb + 3 * 32;
    bf16x8 wah[2], wal[2];
    f32x4 acc[2][4];
    #pragma unroll
    for (int mt = 0; mt < 2; ++mt) {
        const float4* p = (const float4*)(wl + (mt * 16 + l15) * 32 + quad * 8);
        split8(p[0], p[1], wah[mt], wal[mt]);
        float4 bv = *(const float4*)(bl + mt * 16 + quad * 4);
        f32x4 bi; bi[0] = bv.x; bi[1] = bv.y; bi[2] = bv.z; bi[3] = bv.w;
        #pragma unroll
        for (int nt = 0; nt < 4; ++nt) acc[mt][nt] = bi;
    }
    #pragma unroll
    for (int nt = 0; nt < 4; ++nt) {
        int pt = wb + nt * 16 + l15;
        int spl = pt >> 5, t = pt & 31;
        const uint4* xp = (const uint4*)(X + (((long)(b * 4096 + sp0 + spl)) * 32 + t) * 32 + quad * 8);
        bf16x8 bh, blo; unpack8(xp[0], xp[1], bh, blo);
        #pragma unroll
        for (int mt = 0; mt < 2; ++mt) {
            acc[mt][nt] = mfma16(wah[mt], bh, acc[mt][nt]);
            acc[mt][nt] = mfma16(wal[mt], bh, acc[mt][nt]);
            acc[mt][nt] = mfma16(wah[mt], blo, acc[mt][nt]);
        }
    }
    bf16x8 Ah[2], Al[2];
    make_invt_A(l15, quad, Ah, Al);
    bf16x8 xAh, xAl;
    make_invx_A(x0, l15, quad, xAh, xAl);
    #pragma unroll
    for (int half = 0; half < 2; ++half)
        #pragma unroll
        for (int nt2 = 0; nt2 < 2; ++nt2)
            invx_reg(smem, t5v[half][nt2], half, wave, nt2, l15, quad, xAh, xAl);
    __syncthreads();                 // ts complete
    bf16x8 Bh[2][2], Bl[2][2];
    #pragma unroll
    for (int sph = 0; sph < 2; ++sph) {
        int spl = 2 * wave + sph;
        #pragma unroll
        for (int ch = 0; ch < 2; ++ch) {
            float4 q0 = make_float4(0.f, 0.f, 0.f, 0.f), q1 = q0;
            if (quad < 2) {
                const float4* p = (const float4*)((float2*)smem + (ch * 16 + l15) * 66 + spl * 8 + quad * 4);
                q0 = p[0]; q1 = p[1];
            }
            split8(q0, q1, Bh[sph][ch], Bl[sph][ch]);
        }
    }
    __syncthreads();                 // ts reads done; smem free -> packed acts
    #pragma unroll
    for (int sph = 0; sph < 2; ++sph)
        #pragma unroll
        for (int ch = 0; ch < 2; ++ch)
            #pragma unroll
            for (int th = 0; th < 2; ++th) {
                int nt = sph * 2 + th;
                acc[ch][nt] = mfma16(Bh[sph][ch], Ah[th], acc[ch][nt]);
                acc[ch][nt] = mfma16(Bl[sph][ch], Ah[th], acc[ch][nt]);
                acc[ch][nt] = mfma16(Bh[sph][ch], Al[th], acc[ch][nt]);
            }
    #pragma unroll
    for (int mt = 0; mt < 2; ++mt)
        #pragma unroll
        for (int nt = 0; nt < 4; ++nt) gelu4(acc[mt][nt]);
    unsigned* up = (unsigned*)smem;
    #pragma unroll
    for (int mt = 0; mt < 2; ++mt)
        #pragma unroll
        for (int nt = 0; nt < 4; ++nt) {
            int pt = wb + nt * 16 + l15;
            int o0 = mt * 16 + quad * 4;
            *(uint4*)(up + pt * 36 + o0) =
                make_uint4(packhl(acc[mt][nt][0]), packhl(acc[mt][nt][1]),
                           packhl(acc[mt][nt][2]), packhl(acc[mt][nt][3]));
        }
    __syncthreads();
    // head: q1 (MFMA, packed-acts B) + gelu2 + q2 (lane-local + shfl reduce)
    bf16x8 qah[4], qal[4];
    f32x4 qbv[4];
    #pragma unroll
    for (int mt = 0; mt < 4; ++mt) {
        const float4* p = (const float4*)(q1w + (mt * 16 + l15) * 32 + quad * 8);
        split8(p[0], p[1], qah[mt], qal[mt]);
        float4 bv = *(const float4*)(q1b + mt * 16 + quad * 4);
        qbv[mt][0] = bv.x; qbv[mt][1] = bv.y; qbv[mt][2] = bv.z; qbv[mt][3] = bv.w;
    }
    const float* q2l = smem + 9216;
    float q2b0 = q2b[0], q2b1 = q2b[1], q2b2 = q2b[2];
    float oc0[4], oc1[4], oc2[4];
    #pragma unroll
    for (int nt = 0; nt < 4; ++nt) {
        int pt = wb + nt * 16 + l15;
        const uint4* bp = (const uint4*)(up + pt * 36 + quad * 8);
        bf16x8 bh, blo; unpack8(bp[0], bp[1], bh, blo);
        float p0 = 0.f, p1 = 0.f, p2 = 0.f;
        #pragma unroll
        for (int mt = 0; mt < 4; ++mt) {
            f32x4 h = qbv[mt];
            h = mfma16(qah[mt], bh, h);
            h = mfma16(qal[mt], bh, h);
            h = mfma16(qah[mt], blo, h);
            gelu4(h);
            #pragma unroll
            for (int reg = 0; reg < 4; ++reg) {
                int hh = mt * 16 + quad * 4 + reg;
                p0 += q2l[hh] * h[reg];
                p1 += q2l[64 + hh] * h[reg];
                p2 += q2l[128 + hh] * h[reg];
            }
        }
        p0 += __shfl_xor(p0, 16); p0 += __shfl_xor(p0, 32);
        p1 += __shfl_xor(p1, 16); p1 += __shfl_xor(p1, 32);
        p2 += __shfl_xor(p2, 16); p2 += __shfl_xor(p2, 32);
        oc0[nt] = p0 + q2b0; oc1[nt] = p1 + q2b1; oc2[nt] = p2 + q2b2;
    }
    __syncthreads();                 // act reads done; smem[0..863] becomes out-stage
    if (quad == 0) {
        #pragma unroll
        for (int nt = 0; nt < 4; ++nt) {
            int pt = wb + nt * 16 + l15;
            int spl = pt >> 5, t = pt & 31;
            smem[(t * 3 + 0) * 9 + spl] = oc0[nt];
            smem[(t * 3 + 1) * 9 + spl] = oc1[nt];
            smem[(t * 3 + 2) * 9 + spl] = oc2[nt];
        }
    }
    __syncthreads();
    for (int m = tid; m < 768; m += 256) {
        int u = m >> 3, spl = m & 7;
        out[((long)(b * 96 + u)) * 4096 + sp0 + spl] = smem[u * 9 + spl];
    }
}

extern "C" void kernel_launch(void* const* d_in, const int* in_sizes, int n_in,
                              void* d_out, int out_size, void* d_ws, size_t ws_size,
                              hipStream_t stream) {
    const float* xt  = (const float*)d_in[0];
    const float* pw  = (const float*)d_in[1];
    const float* pb  = (const float*)d_in[2];
    const float* swr = (const float*)d_in[3];
    const float* swi = (const float*)d_in[4];
    const float* pww = (const float*)d_in[5];
    const float* pwb = (const float*)d_in[6];
    const float* q1w = (const float*)d_in[7];
    const float* q1b = (const float*)d_in[8];
    const float* q2w = (const float*)d_in[9];
    const float* q2b = (const float*)d_in[10];
    float* out = (float*)d_out;

    unsigned* X  = (unsigned*)d_ws;
    float2* T1 = (float2*)((float*)d_ws + 33554432);
    float2* T2 = (float2*)((float*)T1 + 16777216);
    float2* T3 = (float2*)((float*)T2 + 4194304);
    float2* T4 = (float2*)((float*)T3 + 1048576);

    k_lift<<<4096, 256, 0, stream>>>(xt, pw, pb, X, T1);
    for (int l = 0; l < 4; ++l) {
        k_xdft<<<8192, 256, 0, stream>>>(T1, T2);
        k_ydft<<<4096, 128, 0, stream>>>(T2, T3);
        k_mix2<<<1024, 256, 0, stream>>>(T3, swr, swi, T4, l);
        k_invy<<<4096, 256, 0, stream>>>(T4, T2);
        if (l < 3)
            k_fuse3<<<4096, 256, 0, stream>>>(X, T2, pww, pwb, T1, l);
        else
            k_fuse3_last<<<4096, 256, 0, stream>>>(X, T2, pww, pwb, q1w, q1b, q2w, q2b, out);
    }
}

// Round 10
// 681.490 us; speedup vs baseline: 1.0468x; 1.0381x over previous
//
#include <hip/hip_runtime.h>
#include <math.h>

// FNO3D: B=8, C=3, H=W=64, T=32, WIDTH=32, modes 8x8x8 (4 corners), 4 layers.
// Round 18: EXACT R7/R15 revert (689.0 us config) -- baseline re-confirmation.
// R16's T5-packing regressed (+25 us, latency-hiding VALU removed); R17 showed
// mix2-split + float4-staging are ~+18 us vs R7 OR noise. This round re-runs
// the verified-best configuration byte-for-byte to map the noise floor.
//
// ws floats: X 33,554,432 | T1 16,777,216 | T2 4,194,304 | T3 1,048,576 | T4 1,048,576

#define TWO_PI 6.2831853071795864769f

typedef short bf16x8 __attribute__((ext_vector_type(8)));
typedef float f32x4 __attribute__((ext_vector_type(4)));
typedef float v2f __attribute__((ext_vector_type(2)));

__device__ __forceinline__ f32x4 mfma16(bf16x8 a, bf16x8 b, f32x4 c) {
    return __builtin_amdgcn_mfma_f32_16x16x32_bf16(a, b, c, 0, 0, 0);
}

__device__ __forceinline__ void split8(float4 a, float4 b, bf16x8& h, bf16x8& l) {
    float f[8] = {a.x, a.y, a.z, a.w, b.x, b.y, b.z, b.w};
    #pragma unroll
    for (int i = 0; i < 8; ++i) {
        unsigned u = __float_as_uint(f[i]);
        h[i] = (short)(u >> 16);
        float hf = __uint_as_float(u & 0xFFFF0000u);
        float lf = f[i] - hf;
        l[i] = (short)(__float_as_uint(lf) >> 16);
    }
}

// pack f32 -> u32 (bf16hi<<16 | bf16lo); both truncated like split8
__device__ __forceinline__ unsigned packhl(float f) {
    unsigned u = __float_as_uint(f);
    unsigned hi = u & 0xFFFF0000u;
    float lf = f - __uint_as_float(hi);
    return hi | (__float_as_uint(lf) >> 16);
}

__device__ __forceinline__ void unpack8(uint4 a, uint4 b, bf16x8& h, bf16x8& l) {
    unsigned u[8] = {a.x, a.y, a.z, a.w, b.x, b.y, b.z, b.w};
    #pragma unroll
    for (int i = 0; i < 8; ++i) {
        h[i] = (short)(u[i] >> 16);
        l[i] = (short)(u[i] & 0xFFFFu);
    }
}

__device__ __forceinline__ v2f make2(float x) { v2f r; r.x = x; r.y = x; return r; }
__device__ __forceinline__ v2f fma2(v2f a, v2f b, v2f c) { return __builtin_elementwise_fma(a, b, c); }

// packed gelu via A&S 7.1.26 erf (|err|<=1.5e-7)
__device__ __forceinline__ v2f gelu2(v2f v) {
    v2f u = v * 0.70710678118654752f;
    v2f a = __builtin_elementwise_abs(u);
    v2f den = fma2(a, make2(0.3275911f), make2(1.0f));
    v2f t; t.x = __builtin_amdgcn_rcpf(den.x); t.y = __builtin_amdgcn_rcpf(den.y);
    v2f p = t * (0.254829592f + t * (-0.284496736f + t * (1.421413741f +
            t * (-1.453152027f + t * 1.061405429f))));
    v2f e; e.x = __expf(-u.x * u.x); e.y = __expf(-u.y * u.y);
    v2f m = fma2(-p, e, make2(1.0f));
    v2f erfu = __builtin_elementwise_copysign(m, u);
    return 0.5f * v * (1.0f + erfu);
}

__device__ __forceinline__ void gelu4(f32x4& q) {
    v2f p0; p0.x = q[0]; p0.y = q[1];
    v2f p1; p1.x = q[2]; p1.y = q[3];
    p0 = gelu2(p0); p1 = gelu2(p1);
    q[0] = p0.x; q[1] = p0.y; q[2] = p1.x; q[3] = p1.y;
}

// ---- forward t-DFT matrix A-frag: G[kr][t], kr=l15, t=quad*8+j (K=32 full)
// G[2k][t] = cos(2pi k t/32), G[2k+1][t] = -sin(2pi k t/32)
__device__ __forceinline__ void make_fwd_A(int l15, int quad, bf16x8& Gh, bf16x8& Gl) {
    int k = l15 >> 1;
    float s0, c0, ds, dc;
    __sincosf((float)(k * quad * 8) * (TWO_PI / 32.0f), &s0, &c0);
    __sincosf((float)k * (TWO_PI / 32.0f), &ds, &dc);
    float m[8];
    float cc = c0, ss = s0;
    #pragma unroll
    for (int j = 0; j < 8; ++j) {
        m[j] = (l15 & 1) ? -ss : cc;
        float nc = cc * dc - ss * ds;
        float ns = ss * dc + cc * ds;
        cc = nc; ss = ns;
    }
    split8(make_float4(m[0], m[1], m[2], m[3]),
           make_float4(m[4], m[5], m[6], m[7]), Gh, Gl);
}

// forward t-DFT via MFMA from packed-u32 rows [(spl*32+c)][36] -> T1
__device__ __forceinline__ void fwd_tdft(const unsigned* up, int b, int sp0,
                                         float2* __restrict__ T1,
                                         int wb, int l15, int quad,
                                         bf16x8 Gh, bf16x8 Gl) {
    #pragma unroll
    for (int nt = 0; nt < 4; ++nt) {
        int r = wb + nt * 16 + l15;                 // row = spl*32 + c (wave-local)
        const uint4* p = (const uint4*)(up + r * 36 + quad * 8);
        bf16x8 bh, bl; unpack8(p[0], p[1], bh, bl);
        f32x4 d = {0.f, 0.f, 0.f, 0.f};
        d = mfma16(Gh, bh, d);
        d = mfma16(Gl, bh, d);
        d = mfma16(Gh, bl, d);
        int c = r & 31, spl = r >> 5;
        float4* ob = (float4*)(T1 + ((long)(b * 32 + c) * 4096 + sp0 + spl) * 8 + quad * 2);
        *ob = make_float4(d[0], d[1], d[2], d[3]);
    }
}

// ---- inverse-x DFT matrix A-frag: A[m=(spl,ri_out)][k=(kxi,ri_in)], S folded.
__device__ __forceinline__ void make_invx_A(int x0, int l15, int quad, bf16x8& Ah, bf16x8& Al) {
    int spl = l15 >> 1, ro = l15 & 1;
    float xx = (float)(x0 + spl);
    const float S = 1.0f / 131072.0f;
    float f[8];
    #pragma unroll
    for (int m = 0; m < 4; ++m) {
        int kxi = quad * 4 + m;
        float kx = (float)(kxi < 8 ? kxi : kxi - 16);
        float sn, cs;
        __sincosf(kx * xx * (TWO_PI / 64.0f), &sn, &cs);
        f[2 * m]     = ro ? S * sn : S * cs;
        f[2 * m + 1] = ro ? S * cs : -S * sn;
    }
    split8(make_float4(f[0], f[1], f[2], f[3]),
           make_float4(f[4], f[5], f[6], f[7]), Ah, Al);
}

// inverse-x MFMA from per-thread registers (direct T5 loads): -> ts (f32)
__device__ __forceinline__ void invx_reg(float* smem, const float2 v[4], int half, int wave,
                                         int nt2, int l15, int quad, bf16x8 xAh, bf16x8 xAl) {
    float f[8];
    #pragma unroll
    for (int m = 0; m < 4; ++m) { f[2 * m] = v[m].x; f[2 * m + 1] = v[m].y; }
    bf16x8 bh, bl;
    split8(make_float4(f[0], f[1], f[2], f[3]),
           make_float4(f[4], f[5], f[6], f[7]), bh, bl);
    f32x4 d = {0.f, 0.f, 0.f, 0.f};
    d = mfma16(xAh, bh, d);
    d = mfma16(xAl, bh, d);
    d = mfma16(xAh, bl, d);
    int ol = (wave * 2 + nt2) * 2 + (l15 >> 3), kt = l15 & 7;
    int o = half * 16 + ol;
    #pragma unroll
    for (int reg = 0; reg < 4; ++reg) {
        int m_ = quad * 4 + reg, spl = m_ >> 1, ri = m_ & 1;
        smem[o * 132 + spl * 16 + kt * 2 + ri] = d[reg];
    }
}

// ---- lift: x_t + grid -> p conv -> X(packed) [b][sp][t][c]; fused MFMA t-DFT -> T1 ----
__global__ __launch_bounds__(256) void k_lift(const float* __restrict__ xt,
                                              const float* __restrict__ pw,
                                              const float* __restrict__ pb,
                                              unsigned* __restrict__ X,
                                              float2* __restrict__ T1) {
    __shared__ unsigned xs[9216];       // [(spl*32+c)][36] packed hi|lo
    int gg = blockIdx.x;                // XCD swizzle: batch b = gg&7 stays on one XCD
    int g = ((gg & 7) << 9) | (gg >> 3);
    int spt = g & 511, b = g >> 9;
    int sp0 = spt * 8;
    int y = sp0 >> 6, x0 = sp0 & 63;
    int tid = threadIdx.x;
    int t = tid & 31, spl = tid >> 5;
    int sp = sp0 + spl;
    float a0 = xt[(b * 3 + 0) * 4096 + sp];
    float a1 = xt[(b * 3 + 1) * 4096 + sp];
    float a2 = xt[(b * 3 + 2) * 4096 + sp];
    float gy = y * (1.0f / 63.0f), gx = (x0 + spl) * (1.0f / 63.0f), gt = t * (1.0f / 31.0f);
    float v[32];
    #pragma unroll
    for (int c = 0; c < 32; ++c) {
        const float* w = pw + c * 6;
        v[c] = pb[c] + w[0] * a0 + w[1] * a1 + w[2] * a2
             + w[3] * gy + w[4] * gx + w[5] * gt;
    }
    unsigned pk[32];
    #pragma unroll
    for (int c = 0; c < 32; ++c) pk[c] = packhl(v[c]);
    unsigned* xg2 = X + (((long)(b * 4096 + sp)) * 32 + t) * 32;
    #pragma unroll
    for (int j = 0; j < 8; ++j)
        ((uint4*)xg2)[j] = make_uint4(pk[4*j], pk[4*j+1], pk[4*j+2], pk[4*j+3]);
    #pragma unroll
    for (int c = 0; c < 32; ++c)
        xs[(spl * 32 + c) * 36 + t] = pk[c];          // 2-way bank alias: free
    int wave = tid >> 6, lane = tid & 63, l15 = lane & 15, quad = lane >> 4;
    bf16x8 Gh, Gl; make_fwd_A(l15, quad, Gh, Gl);
    __syncthreads();
    fwd_tdft(xs, b, sp0, T1, wave * 64, l15, quad, Gh, Gl);
}

// ------- forward x-DFT (E/O split): T1 -> T2 (16 modes) -------
__global__ __launch_bounds__(256) void k_xdft(const float2* __restrict__ T1, float2* __restrict__ T2) {
    __shared__ float2 s[1024];
    __shared__ float2 tw[64];
    int g = blockIdx.x;              // bc*32 + ypair ; 8192 blocks
    int ypair = g & 31; int bc = g >> 5;
    long base = ((long)bc * 64 + ypair * 2) * 512;
    int tid = threadIdx.x;
    for (int k = tid; k < 1024; k += 256) s[k] = T1[base + k];
    if (tid < 64) { float sn, cs; __sincosf(tid * (TWO_PI / 64.0f), &sn, &cs); tw[tid] = make_float2(cs, sn); }
    __syncthreads();
    // in-place butterfly: x<32 -> E at x, O at x+32 (per half-row)
    #pragma unroll
    for (int r = 0; r < 2; ++r) {
        int j = tid + r * 256;       // 512 pairs: (half, x<32, kt)
        int half = j >> 8, rem = j & 255;
        int idx = half * 512 + rem;
        float2 a = s[idx], b2 = s[idx + 256];
        s[idx] = make_float2(a.x + b2.x, a.y + b2.y);
        s[idx + 256] = make_float2(a.x - b2.x, a.y - b2.y);
    }
    __syncthreads();
    int half = tid >> 7, jj = tid & 127;
    int kxi = jj >> 3, kt = jj & 7;
    int kx = kxi < 8 ? kxi : kxi + 48;
    const float2* row = s + half * 512 + (kx & 1) * 256;
    float sr = 0.f, si = 0.f;
    for (int x = 0; x < 32; ++x) {
        float2 w = tw[(kx * x) & 63];
        float2 a = row[x * 8 + kt];
        sr += a.x * w.x + a.y * w.y;
        si += a.y * w.x - a.x * w.y;
    }
    T2[((long)bc * 64 + ypair * 2 + half) * 128 + jj] = make_float2(sr, si);
}

// ------- forward y-DFT (E/O split): T2 -> T3 (16 modes) -------
__global__ __launch_bounds__(128) void k_ydft(const float2* __restrict__ T2, float2* __restrict__ T3) {
    __shared__ float2 s[512];
    __shared__ float2 tw[64];
    int g = blockIdx.x;              // bc*16 + kx ; 4096 blocks
    int kx = g & 15; int bc = g >> 4;
    int tid = threadIdx.x;
    for (int k = tid; k < 512; k += 128) {
        int y = k >> 3, kt = k & 7;
        s[k] = T2[((long)bc * 64 + y) * 128 + kx * 8 + kt];
    }
    if (tid < 64) { float sn, cs; __sincosf(tid * (TWO_PI / 64.0f), &sn, &cs); tw[tid] = make_float2(cs, sn); }
    __syncthreads();
    #pragma unroll
    for (int r = 0; r < 2; ++r) {
        int j = tid + r * 128;       // 256 pairs: y<32 x kt
        float2 a = s[j], b2 = s[j + 256];
        s[j] = make_float2(a.x + b2.x, a.y + b2.y);
        s[j + 256] = make_float2(a.x - b2.x, a.y - b2.y);
    }
    __syncthreads();
    int kyi = tid >> 3, kt = tid & 7;
    int ky = kyi < 8 ? kyi : kyi + 48;
    const float2* row = s + (ky & 1) * 256;
    float sr = 0.f, si = 0.f;
    for (int y = 0; y < 32; ++y) {
        float2 w = tw[(ky * y) & 63];
        float2 a = row[y * 8 + kt];
        sr += a.x * w.x + a.y * w.y;
        si += a.y * w.x - a.x * w.y;
    }
    T3[((long)bc * 256 + kyi * 16 + kx) * 8 + kt] = make_float2(sr, si);
}

// -------- mode mix (mode-major, b-loop amortizes weight reads) --------
__global__ __launch_bounds__(256) void k_mix2(const float2* __restrict__ T3,
                                              const float* __restrict__ wr,
                                              const float* __restrict__ wi,
                                              float2* __restrict__ T4, int layer) {
    __shared__ float2 s[2304];
    int mode = blockIdx.x;           // 256 blocks
    int kyi = mode >> 4, kxi = mode & 15;
    int tid = threadIdx.x;
    {
        int bb = tid >> 5, i = tid & 31;
        const float2* src = T3 + ((long)(bb * 32 + i) * 256 + mode) * 8;
        float2* dst = s + (i * 8 + bb) * 9;
        #pragma unroll
        for (int k = 0; k < 8; ++k) dst[k] = src[k];
    }
    __syncthreads();
    int corner = (kyi >= 8 ? 1 : 0) + (kxi >= 8 ? 2 : 0);
    long wbase = (long)(layer * 4 + corner) * 524288 + (long)(kyi & 7) * 64 + (long)(kxi & 7) * 8;
    int o = tid >> 3, kt = tid & 7;
    long wb = wbase + (long)o * 512 + kt;
    float2 acc[8];
    #pragma unroll
    for (int bb = 0; bb < 8; ++bb) acc[bb] = make_float2(0.f, 0.f);
    for (int i = 0; i < 32; ++i) {
        float r = wr[wb + (long)i * 16384], im = wi[wb + (long)i * 16384];
        #pragma unroll
        for (int bb = 0; bb < 8; ++bb) {
            float2 a = s[(i * 8 + bb) * 9 + kt];
            acc[bb].x += a.x * r - a.y * im;
            acc[bb].y += a.x * im + a.y * r;
        }
    }
    #pragma unroll
    for (int bb = 0; bb < 8; ++bb)
        T4[((long)(bb * 32 + o) * 256 + mode) * 8 + kt] = acc[bb];
}

// ------- inverse y (P/M pairing): T4 -> T5 (T2 space) -------
__global__ __launch_bounds__(256) void k_invy(const float2* __restrict__ T4, float2* __restrict__ T5) {
    __shared__ float2 s[128];
    __shared__ float2 tw[64];
    __shared__ float2 pmP[56], pmM[56];   // j=1..7 x kt
    int g = blockIdx.x;              // bc*16 + kx ; 4096 blocks
    int kx = g & 15; int bc = g >> 4;
    int tid = threadIdx.x;
    if (tid < 128) {
        int kyi = tid >> 3, kt = tid & 7;
        s[tid] = T4[((long)bc * 256 + kyi * 16 + kx) * 8 + kt];
    } else if (tid < 192) {
        int m = tid - 128; float sn, cs; __sincosf(m * (TWO_PI / 64.0f), &sn, &cs); tw[m] = make_float2(cs, sn);
    }
    __syncthreads();
    if (tid < 56) {
        int j = (tid >> 3) + 1, kt = tid & 7;
        float2 a = s[j * 8 + kt], b2 = s[(16 - j) * 8 + kt];
        pmP[tid] = make_float2(a.x + b2.x, a.y + b2.y);
        pmM[tid] = make_float2(a.x - b2.x, a.y - b2.y);
    }
    __syncthreads();
    #pragma unroll
    for (int r = 0; r < 2; ++r) {
        int j = tid + r * 256;
        int y = j >> 3, kt = j & 7;
        float2 A0 = s[kt], A8 = s[64 + kt];
        float2 w8 = tw[(8 * y) & 63];
        float sr = A0.x + A8.x * w8.x + A8.y * w8.y;
        float si = A0.y + A8.y * w8.x - A8.x * w8.y;
        #pragma unroll
        for (int jj = 1; jj < 8; ++jj) {
            float2 w = tw[(jj * y) & 63];
            float2 P = pmP[(jj - 1) * 8 + kt], M = pmM[(jj - 1) * 8 + kt];
            sr += P.x * w.x - M.y * w.y;
            si += P.y * w.x + M.x * w.y;
        }
        T5[((long)bc * 64 + y) * 128 + kx * 8 + kt] = make_float2(sr, si);
    }
}

// ---- inverse-t DFT matrix frags (used as MFMA **B** operand, values = M[t][kr]):
// lane n=t (=l15, t-half th), k-slot kr = quad*8+j; quads 2,3 zero (K pad 16->32).
__device__ __forceinline__ void make_invt_A(int l15, int quad, bf16x8 Ah[2], bf16x8 Al[2]) {
    #pragma unroll
    for (int th = 0; th < 2; ++th) {
        float m[8];
        if (quad < 2) {
            int tt = th * 16 + l15;
            #pragma unroll
            for (int kk = 0; kk < 4; ++kk) {
                int k = quad * 4 + kk;
                float sn, cs;
                __sincosf((float)(k * tt) * (TWO_PI / 32.0f), &sn, &cs);
                float w = k ? 2.0f : 1.0f;
                m[2 * kk] = w * cs;
                m[2 * kk + 1] = -w * sn;
            }
        } else {
            #pragma unroll
            for (int j = 0; j < 8; ++j) m[j] = 0.f;
        }
        split8(make_float4(m[0], m[1], m[2], m[3]),
               make_float4(m[4], m[5], m[6], m[7]), Ah[th], Al[th]);
    }
}

// ---- fuse3: MFMA pointwise + MFMA inverse-x (reg-direct T5) + transposed
//      MFMA inverse-t (direct accumulate) + gelu2; X update; MFMA fwd t-DFT ----
__global__ __launch_bounds__(256) void k_fuse3(unsigned* __restrict__ X, const float2* __restrict__ T5,
                                               const float* __restrict__ pww,
                                               const float* __restrict__ pwb,
                                               float2* __restrict__ T1, int layer) {
    __shared__ float smem[9216];     // ts [0..4223] | packed acts/D 256x36 u32 (union)
    int gg = blockIdx.x;             // XCD swizzle: batch b = gg&7 stays on one XCD
    int g = ((gg & 7) << 9) | (gg >> 3);
    int spt = g & 511, b = g >> 9;
    int sp0 = spt * 8;
    int y = sp0 >> 6, x0 = sp0 & 63;
    int tid = threadIdx.x;
    int wave = tid >> 6, lane = tid & 63, l15 = lane & 15, quad = lane >> 4;
    int wb = wave * 64;
    // direct T5 loads (each cell consumed by exactly this thread); issued
    // at entry so HBM/L2 latency hides under the pointwise MFMA section
    float2 t5v[2][2][4];
    #pragma unroll
    for (int half = 0; half < 2; ++half)
        #pragma unroll
        for (int nt2 = 0; nt2 < 2; ++nt2) {
            int ol = (wave * 2 + nt2) * 2 + (l15 >> 3);
            const float2* rp = T5 + ((long)((b * 32 + half * 16 + ol) * 64 + y)) * 128 + (l15 & 7);
            #pragma unroll
            for (int m = 0; m < 4; ++m)
                t5v[half][nt2][m] = rp[(quad * 4 + m) * 8];
        }
    const float* wl = pww + layer * 1024;
    const float* bl = pwb + layer * 32;
    bf16x8 wah[2], wal[2];
    f32x4 acc[2][4];
    #pragma unroll
    for (int mt = 0; mt < 2; ++mt) {
        const float4* p = (const float4*)(wl + (mt * 16 + l15) * 32 + quad * 8);
        split8(p[0], p[1], wah[mt], wal[mt]);
        float4 bv = *(const float4*)(bl + mt * 16 + quad * 4);
        f32x4 bi; bi[0] = bv.x; bi[1] = bv.y; bi[2] = bv.z; bi[3] = bv.w;
        #pragma unroll
        for (int nt = 0; nt < 4; ++nt) acc[mt][nt] = bi;
    }
    #pragma unroll
    for (int nt = 0; nt < 4; ++nt) {
        int pt = wb + nt * 16 + l15;
        int spl = pt >> 5, t = pt & 31;
        const uint4* xp = (const uint4*)(X + (((long)(b * 4096 + sp0 + spl)) * 32 + t) * 32 + quad * 8);
        bf16x8 bh, blo; unpack8(xp[0], xp[1], bh, blo);
        #pragma unroll
        for (int mt = 0; mt < 2; ++mt) {
            acc[mt][nt] = mfma16(wah[mt], bh, acc[mt][nt]);
            acc[mt][nt] = mfma16(wal[mt], bh, acc[mt][nt]);
            acc[mt][nt] = mfma16(wah[mt], blo, acc[mt][nt]);
        }
    }
    bf16x8 Ah[2], Al[2];
    make_invt_A(l15, quad, Ah, Al);
    bf16x8 xAh, xAl;
    make_invx_A(x0, l15, quad, xAh, xAl);
    // inverse-x from registers -> ts (no staging barriers)
    #pragma unroll
    for (int half = 0; half < 2; ++half)
        #pragma unroll
        for (int nt2 = 0; nt2 < 2; ++nt2)
            invx_reg(smem, t5v[half][nt2], half, wave, nt2, l15, quad, xAh, xAl);
    __syncthreads();                 // ts complete
    // spectrum frags (A operand of the transposed inverse-t)
    bf16x8 Bh[2][2], Bl[2][2];
    #pragma unroll
    for (int sph = 0; sph < 2; ++sph) {
        int spl = 2 * wave + sph;
        #pragma unroll
        for (int ch = 0; ch < 2; ++ch) {
            float4 q0 = make_float4(0.f, 0.f, 0.f, 0.f), q1 = q0;
            if (quad < 2) {
                const float4* p = (const float4*)((float2*)smem + (ch * 16 + l15) * 66 + spl * 8 + quad * 4);
                q0 = p[0]; q1 = p[1];
            }
            split8(q0, q1, Bh[sph][ch], Bl[sph][ch]);
        }
    }
    __syncthreads();                 // ts reads done; smem free -> packed acts
    // transposed inverse-t: acc[ch][sph*2+th] += S^T x M^T  (register-direct)
    #pragma unroll
    for (int sph = 0; sph < 2; ++sph)
        #pragma unroll
        for (int ch = 0; ch < 2; ++ch)
            #pragma unroll
            for (int th = 0; th < 2; ++th) {
                int nt = sph * 2 + th;
                acc[ch][nt] = mfma16(Bh[sph][ch], Ah[th], acc[ch][nt]);
                acc[ch][nt] = mfma16(Bl[sph][ch], Ah[th], acc[ch][nt]);
                acc[ch][nt] = mfma16(Bh[sph][ch], Al[th], acc[ch][nt]);
            }
    bf16x8 Gh, Gl; make_fwd_A(l15, quad, Gh, Gl);
    #pragma unroll
    for (int mt = 0; mt < 2; ++mt)
        #pragma unroll
        for (int nt = 0; nt < 4; ++nt) gelu4(acc[mt][nt]);
    unsigned* up = (unsigned*)smem;
    #pragma unroll
    for (int mt = 0; mt < 2; ++mt)
        #pragma unroll
        for (int nt = 0; nt < 4; ++nt) {
            int pt = wb + nt * 16 + l15;
            int spl = pt >> 5, t = pt & 31;
            int o0 = mt * 16 + quad * 4;
            unsigned pk0 = packhl(acc[mt][nt][0]), pk1 = packhl(acc[mt][nt][1]);
            unsigned pk2 = packhl(acc[mt][nt][2]), pk3 = packhl(acc[mt][nt][3]);
            *(uint4*)(X + (((long)(b * 4096 + sp0 + spl)) * 32 + t) * 32 + o0) =
                make_uint4(pk0, pk1, pk2, pk3);
            // transposed packed store (2-way bank alias: free)
            up[(spl * 32 + o0 + 0) * 36 + t] = pk0;
            up[(spl * 32 + o0 + 1) * 36 + t] = pk1;
            up[(spl * 32 + o0 + 2) * 36 + t] = pk2;
            up[(spl * 32 + o0 + 3) * 36 + t] = pk3;
        }
    __syncthreads();
    // MFMA forward t-DFT for next layer
    fwd_tdft(up, b, sp0, T1, wb, l15, quad, Gh, Gl);
}

// ---- fuse3_last: MFMA layer-3 pointwise + inverse-x (reg-direct) + transposed
//      inverse-t + q1 head (packed acts) + q2 -> out ----
__global__ __launch_bounds__(256) void k_fuse3_last(const unsigned* __restrict__ X, const float2* __restrict__ T5,
                                                    const float* __restrict__ pww, const float* __restrict__ pwb,
                                                    const float* __restrict__ q1w, const float* __restrict__ q1b,
                                                    const float* __restrict__ q2w, const float* __restrict__ q2b,
                                                    float* __restrict__ out) {
    __shared__ float smem[9408];     // ts | packed acts 256x36 (union); q2w at 9216
    int gg = blockIdx.x;             // XCD swizzle
    int g = ((gg & 7) << 9) | (gg >> 3);
    int spt = g & 511, b = g >> 9;
    int sp0 = spt * 8;
    int y = sp0 >> 6, x0 = sp0 & 63;
    int tid = threadIdx.x;
    int wave = tid >> 6, lane = tid & 63, l15 = lane & 15, quad = lane >> 4;
    int wb = wave * 64;
    float2 t5v[2][2][4];
    #pragma unroll
    for (int half = 0; half < 2; ++half)
        #pragma unroll
        for (int nt2 = 0; nt2 < 2; ++nt2) {
            int ol = (wave * 2 + nt2) * 2 + (l15 >> 3);
            const float2* rp = T5 + ((long)((b * 32 + half * 16 + ol) * 64 + y)) * 128 + (l15 & 7);
            #pragma unroll
            for (int m = 0; m < 4; ++m)
                t5v[half][nt2][m] = rp[(quad * 4 + m) * 8];
        }
    if (tid < 192) smem[9216 + tid] = q2w[tid];
    const float* wl = pww + 3 * 1024;
    const float* bl = pwb + 3 * 32;
    bf16x8 wah[2], wal[2];
    f32x4 acc[2][4];
    #pragma unroll
    for (int mt = 0; mt < 2; ++mt) {
        const float4* p = (const float4*)(wl + (mt * 16 + l15) * 32 + quad * 8);
        split8(p[0], p[1], wah[mt], wal[mt]);
        float4 bv = *(const float4*)(bl + mt * 16 + quad * 4);
        f32x4 bi; bi[0] = bv.x; bi[1] = bv.y; bi[2] = bv.z; bi[3] = bv.w;
        #pragma unroll
        for (int nt = 0; nt < 4; ++nt) acc[mt][nt] = bi;
    }
    #pragma unroll
    for (int nt = 0; nt < 4; ++nt) {
        int pt = wb + nt * 16 + l15;
        int spl = pt >> 5, t = pt & 31;
        const uint4* xp = (const uint4*)(X + (((long)(b * 4096 + sp0 + spl)) * 32 + t) * 32 + quad * 8);
        bf16x8 bh, blo; unpack8(xp[0], xp[1], bh, blo);
        #pragma unroll
        for (int mt = 0; mt < 2; ++mt) {
            acc[mt][nt] = mfma16(wah[mt], bh, acc[mt][nt]);
            acc[mt][nt] = mfma16(wal[mt], bh, acc[mt][nt]);
            acc[mt][nt] = mfma16(wah[mt], blo, acc[mt][nt]);
        }
    }
    bf16x8 Ah[2], Al[2];
    make_invt_A(l15, quad, Ah, Al);
    bf16x8 xAh, xAl;
    make_invx_A(x0, l15, quad, xAh, xAl);
    #pragma unroll
    for (int half = 0; half < 2; ++half)
        #pragma unroll
        for (int nt2 = 0; nt2 < 2; ++nt2)
            invx_reg(smem, t5v[half][nt2], half, wave, nt2, l15, quad, xAh, xAl);
    __syncthreads();                 // ts complete
    bf16x8 Bh[2][2], Bl[2][2];
    #pragma unroll
    for (int sph = 0; sph < 2; ++sph) {
        int spl = 2 * wave + sph;
        #pragma unroll
        for (int ch = 0; ch < 2; ++ch) {
            float4 q0 = make_float4(0.f, 0.f, 0.f, 0.f), q1 = q0;
            if (quad < 2) {
                const float4* p = (const float4*)((float2*)smem + (ch * 16 + l15) * 66 + spl * 8 + quad * 4);
                q0 = p[0]; q1 = p[1];
            }
            split8(q0, q1, Bh[sph][ch], Bl[sph][ch]);
        }
    }
    __syncthreads();                 // ts reads done; smem free -> packed acts
    #pragma unroll
    for (int sph = 0; sph < 2; ++sph)
        #pragma unroll
        for (int ch = 0; ch < 2; ++ch)
            #pragma unroll
            for (int th = 0; th < 2; ++th) {
                int nt = sph * 2 + th;
                acc[ch][nt] = mfma16(Bh[sph][ch], Ah[th], acc[ch][nt]);
                acc[ch][nt] = mfma16(Bl[sph][ch], Ah[th], acc[ch][nt]);
                acc[ch][nt] = mfma16(Bh[sph][ch], Al[th], acc[ch][nt]);
            }
    #pragma unroll
    for (int mt = 0; mt < 2; ++mt)
        #pragma unroll
        for (int nt = 0; nt < 4; ++nt) gelu4(acc[mt][nt]);
    unsigned* up = (unsigned*)smem;
    #pragma unroll
    for (int mt = 0; mt < 2; ++mt)
        #pragma unroll
        for (int nt = 0; nt < 4; ++nt) {
            int pt = wb + nt * 16 + l15;
            int o0 = mt * 16 + quad * 4;
            *(uint4*)(up + pt * 36 + o0) =
                make_uint4(packhl(acc[mt][nt][0]), packhl(acc[mt][nt][1]),
                           packhl(acc[mt][nt][2]), packhl(acc[mt][nt][3]));
        }
    __syncthreads();
    // head: q1 (MFMA, packed-acts B) + gelu2 + q2 (lane-local + shfl reduce)
    bf16x8 qah[4], qal[4];
    f32x4 qbv[4];
    #pragma unroll
    for (int mt = 0; mt < 4; ++mt) {
        const float4* p = (const float4*)(q1w + (mt * 16 + l15) * 32 + quad * 8);
        split8(p[0], p[1], qah[mt], qal[mt]);
        float4 bv = *(const float4*)(q1b + mt * 16 + quad * 4);
        qbv[mt][0] = bv.x; qbv[mt][1] = bv.y; qbv[mt][2] = bv.z; qbv[mt][3] = bv.w;
    }
    const float* q2l = smem + 9216;
    float q2b0 = q2b[0], q2b1 = q2b[1], q2b2 = q2b[2];
    float oc0[4], oc1[4], oc2[4];
    #pragma unroll
    for (int nt = 0; nt < 4; ++nt) {
        int pt = wb + nt * 16 + l15;
        const uint4* bp = (const uint4*)(up + pt * 36 + quad * 8);
        bf16x8 bh, blo; unpack8(bp[0], bp[1], bh, blo);
        float p0 = 0.f, p1 = 0.f, p2 = 0.f;
        #pragma unroll
        for (int mt = 0; mt < 4; ++mt) {
            f32x4 h = qbv[mt];
            h = mfma16(qah[mt], bh, h);
            h = mfma16(qal[mt], bh, h);
            h = mfma16(qah[mt], blo, h);
            gelu4(h);
            #pragma unroll
            for (int reg = 0; reg < 4; ++reg) {
                int hh = mt * 16 + quad * 4 + reg;
                p0 += q2l[hh] * h[reg];
                p1 += q2l[64 + hh] * h[reg];
                p2 += q2l[128 + hh] * h[reg];
            }
        }
        p0 += __shfl_xor(p0, 16); p0 += __shfl_xor(p0, 32);
        p1 += __shfl_xor(p1, 16); p1 += __shfl_xor(p1, 32);
        p2 += __shfl_xor(p2, 16); p2 += __shfl_xor(p2, 32);
        oc0[nt] = p0 + q2b0; oc1[nt] = p1 + q2b1; oc2[nt] = p2 + q2b2;
    }
    __syncthreads();                 // act reads done; smem[0..863] becomes out-stage
    if (quad == 0) {
        #pragma unroll
        for (int nt = 0; nt < 4; ++nt) {
            int pt = wb + nt * 16 + l15;
            int spl = pt >> 5, t = pt & 31;
            smem[(t * 3 + 0) * 9 + spl] = oc0[nt];
            smem[(t * 3 + 1) * 9 + spl] = oc1[nt];
            smem[(t * 3 + 2) * 9 + spl] = oc2[nt];
        }
    }
    __syncthreads();
    for (int m = tid; m < 768; m += 256) {
        int u = m >> 3, spl = m & 7;
        out[((long)(b * 96 + u)) * 4096 + sp0 + spl] = smem[u * 9 + spl];
    }
}

extern "C" void kernel_launch(void* const* d_in, const int* in_sizes, int n_in,
                              void* d_out, int out_size, void* d_ws, size_t ws_size,
                              hipStream_t stream) {
    const float* xt  = (const float*)d_in[0];
    const float* pw  = (const float*)d_in[1];
    const float* pb  = (const float*)d_in[2];
    const float* swr = (const float*)d_in[3];
    const float* swi = (const float*)d_in[4];
    const float* pww = (const float*)d_in[5];
    const float* pwb = (const float*)d_in[6];
    const float* q1w = (const float*)d_in[7];
    const float* q1b = (const float*)d_in[8];
    const float* q2w = (const float*)d_in[9];
    const float* q2b = (const float*)d_in[10];
    float* out = (float*)d_out;

    unsigned* X  = (unsigned*)d_ws;
    float2* T1 = (float2*)((float*)d_ws + 33554432);
    float2* T2 = (float2*)((float*)T1 + 16777216);
    float2* T3 = (float2*)((float*)T2 + 4194304);
    float2* T4 = (float2*)((float*)T3 + 1048576);

    k_lift<<<4096, 256, 0, stream>>>(xt, pw, pb, X, T1);
    for (int l = 0; l < 4; ++l) {
        k_xdft<<<8192, 256, 0, stream>>>(T1, T2);
        k_ydft<<<4096, 128, 0, stream>>>(T2, T3);
        k_mix2<<<256, 256, 0, stream>>>(T3, swr, swi, T4, l);
        k_invy<<<4096, 256, 0, stream>>>(T4, T2);
        if (l < 3)
            k_fuse3<<<4096, 256, 0, stream>>>(X, T2, pww, pwb, T1, l);
        else
            k_fuse3_last<<<4096, 256, 0, stream>>>(X, T2, pww, pwb, q1w, q1b, q2w, q2b, out);
    }
}